// Round 1
// baseline (197.172 us; speedup 1.0000x reference)
//
#include <hip/hip_runtime.h>
#include <math.h>

#define BS 32
#define NM 64
#define NA 8400
#define NC 80
#define TOPKK 13
#define N_TOT (BS * NA)

// CIoU (box1 = gt, box2 = pred), clipped at 0 — transcribed 1:1 from the
// reference _ciou with eps=1e-7, then jnp.clip(x, 0).
__device__ __forceinline__ float ciou_clip(float gx1, float gy1, float gx2, float gy2,
                                           float px1, float py1, float px2, float py2) {
    const float eps = 1e-7f;
    float w1 = gx2 - gx1, h1 = gy2 - gy1 + eps;
    float w2 = px2 - px1, h2 = py2 - py1 + eps;
    float iw = fmaxf(fminf(gx2, px2) - fmaxf(gx1, px1), 0.f);
    float ih = fmaxf(fminf(gy2, py2) - fmaxf(gy1, py1), 0.f);
    float inter = iw * ih;
    float uni = w1 * h1 + w2 * h2 - inter + eps;
    float iou = inter / uni;
    float cw = fmaxf(gx2, px2) - fminf(gx1, px1);
    float ch = fmaxf(gy2, py2) - fminf(gy1, py1);
    float c2 = cw * cw + ch * ch + eps;
    float dx = px1 + px2 - gx1 - gx2;
    float dy = py1 + py2 - gy1 - gy2;
    float rho2 = (dx * dx + dy * dy) * 0.25f;
    float dat = atanf(w2 / h2) - atanf(w1 / h1);
    float v = 0.4052847345693511f * dat * dat;  // 4/pi^2
    float al = v / (v - iou + 1.0000001f);      // 1.0 + eps, stop_gradient irrelevant fwd
    return fmaxf(iou - (rho2 / c2 + v * al), 0.f);
}

// Kernel 1: one block per (b, m). Build the align_metric row in LDS, take
// exact top-13 (value desc, index asc tie-break, matching jax.lax.top_k),
// and scatter candidate assignments.
__global__ __launch_bounds__(256) void k_topk(
    const float* __restrict__ pd_scores,
    const float* __restrict__ pd_bboxes,
    const float* __restrict__ anc,
    const int* __restrict__ gt_labels,
    const float* __restrict__ gt_bboxes,
    const float* __restrict__ mask_gt,
    int* __restrict__ fg,
    int* __restrict__ assignm) {
    const int bm = blockIdx.x;
    // mask_gt == 0: topk_idxs forced to 0 -> count=13 at idx0 -> mask_topk=0
    // everywhere. Row contributes nothing. Uniform early exit.
    if (mask_gt[bm] <= 0.f) return;

    __shared__ unsigned int sbits[NA];
    __shared__ unsigned long long sred[256];
    __shared__ int schosen[TOPKK];

    const int tid = threadIdx.x;
    const int b = bm / NM;
    const int m = bm - b * NM;
    const float4 g = ((const float4*)gt_bboxes)[bm];
    const int lbl = gt_labels[bm];
    const float4* pb = (const float4*)(pd_bboxes + (size_t)b * NA * 4);
    const float* ps = pd_scores + (size_t)b * NA * NC + lbl;

    for (int a = tid; a < NA; a += 256) {
        float ax = anc[2 * a], ay = anc[2 * a + 1];
        float dmin = fminf(fminf(ax - g.x, ay - g.y), fminf(g.z - ax, g.w - ay));
        float metric = 0.f;
        if (dmin > 1e-9f) {  // mask_in_gts (EPS = 1e-9)
            float4 p = pb[a];
            float ov = ciou_clip(g.x, g.y, g.z, g.w, p.x, p.y, p.z, p.w);
            float s = ps[(size_t)a * NC];
            metric = s * powf(ov, 6.0f);  // score^1 * overlap^6
        }
        sbits[a] = __float_as_uint(metric);  // all metrics >= 0: bits monotone
    }
    __syncthreads();

    for (int k = 0; k < TOPKK; ++k) {
        unsigned long long best = 0ull;
        for (int a = tid; a < NA; a += 256) {
            unsigned int bits = sbits[a];
            if (bits != 0xFFFFFFFFu) {  // sentinel: already picked
                unsigned long long key =
                    ((unsigned long long)bits << 32) | (unsigned)(NA - 1 - a);
                if (key > best) best = key;
            }
        }
        sred[tid] = best;
        __syncthreads();
#pragma unroll
        for (int off = 128; off > 0; off >>= 1) {
            if (tid < off) {
                unsigned long long o = sred[tid + off];
                if (o > sred[tid]) sred[tid] = o;
            }
            __syncthreads();
        }
        if (tid == 0) {
            int a = NA - 1 - (int)(sred[0] & 0xFFFFFFFFull);
            schosen[k] = a;
            sbits[a] = 0xFFFFFFFFu;
        }
        __syncthreads();
    }

    // Scatter: topk indices are distinct (count==1), filter by mask_in_gts.
    if (tid < TOPKK) {
        int a = schosen[tid];
        float ax = anc[2 * a], ay = anc[2 * a + 1];
        float dmin = fminf(fminf(ax - g.x, ay - g.y), fminf(g.z - ax, g.w - ay));
        if (dmin > 1e-9f) {
            atomicAdd(&fg[b * NA + a], 1);
            atomicMin(&assignm[b * NA + a], m);
        }
    }
}

// Kernel 2: one thread per (b, a). Resolve multi-assignment via masked-overlap
// argmax (tie -> lowest m, matching jnp.argmax), recompute assigned
// metric/overlap, reduce pos_align/pos_ovl per (b, m).
__global__ __launch_bounds__(256) void k_assign(
    const float* __restrict__ pd_scores,
    const float* __restrict__ pd_bboxes,
    const float* __restrict__ anc,
    const int* __restrict__ gt_labels,
    const float* __restrict__ gt_bboxes,
    const float* __restrict__ mask_gt,
    int* fg_inout,      // in: candidate count; out: fg flag (0/1)
    int* assign_inout,  // in: min-m candidate; out: final target gt idx
    float* __restrict__ mval,
    float* __restrict__ pos_align,
    float* __restrict__ pos_ovl) {
    int i = blockIdx.x * blockDim.x + threadIdx.x;
    if (i >= N_TOT) return;
    int b = i / NA, a = i - b * NA;

    int f = fg_inout[i];
    if (f <= 0) {
        fg_inout[i] = 0;
        assign_inout[i] = 0;  // argmax of all-zero mask_pos column = 0
        mval[i] = 0.f;
        return;
    }

    float ax = anc[2 * a], ay = anc[2 * a + 1];
    float4 p = ((const float4*)pd_bboxes)[i];

    int m;
    if (f == 1) {
        m = assign_inout[i];
    } else {
        // multi: is_max = one_hot(argmax_m overlaps[b,:,a]); ties -> first m
        float best = -1.f;
        int bestm = 0;
        for (int mm = 0; mm < NM; ++mm) {
            float4 g = ((const float4*)gt_bboxes)[b * NM + mm];
            float dmin = fminf(fminf(ax - g.x, ay - g.y), fminf(g.z - ax, g.w - ay));
            float ov = 0.f;
            if (dmin > 1e-9f && mask_gt[b * NM + mm] > 0.f)
                ov = ciou_clip(g.x, g.y, g.z, g.w, p.x, p.y, p.z, p.w);
            if (ov > best) { best = ov; bestm = mm; }
        }
        m = bestm;
    }

    // masked align_metric / overlap at the final (b, m, a)
    float4 g = ((const float4*)gt_bboxes)[b * NM + m];
    float dmin = fminf(fminf(ax - g.x, ay - g.y), fminf(g.z - ax, g.w - ay));
    float mv = 0.f, ovv = 0.f;
    if (dmin > 1e-9f && mask_gt[b * NM + m] > 0.f) {
        ovv = ciou_clip(g.x, g.y, g.z, g.w, p.x, p.y, p.z, p.w);
        float s = pd_scores[(size_t)i * NC + gt_labels[b * NM + m]];
        mv = s * powf(ovv, 6.0f);
    }

    fg_inout[i] = 1;
    assign_inout[i] = m;
    mval[i] = mv;
    // values >= 0 -> int compare == float compare; order-independent.
    atomicMax((int*)&pos_align[b * NM + m], __float_as_int(mv));
    atomicMax((int*)&pos_ovl[b * NM + m], __float_as_int(ovv));
}

// Kernel 3: per-anchor finalize: labels, bboxes, fg, idx outputs + norm/label
// staged into ws for the scores kernel. fgm/mval arrays are reused in place.
__global__ __launch_bounds__(256) void k_final(
    const int* __restrict__ gt_labels,
    const float* __restrict__ gt_bboxes,
    int* fgm_lblw,    // in: fg flag; out: label if fg else -1
    const int* __restrict__ tgt,
    float* mval_norm, // in: metric val; out: norm
    const float* __restrict__ pos_align,
    const float* __restrict__ pos_ovl,
    float* __restrict__ out) {
    int i = blockIdx.x * blockDim.x + threadIdx.x;
    if (i >= N_TOT) return;
    int b = i / NA;
    int m = tgt[i];
    int f = fgm_lblw[i];
    int lbl = gt_labels[b * NM + m];
    lbl = lbl < 0 ? 0 : lbl;
    float4 box = ((const float4*)gt_bboxes)[b * NM + m];
    float nrm = 0.f;
    if (f) nrm = mval_norm[i] * pos_ovl[b * NM + m] / (pos_align[b * NM + m] + 1e-9f);

    out[i] = (float)lbl;                          // target_labels
    ((float4*)(out + N_TOT))[i] = box;            // target_bboxes
    out[(size_t)85 * N_TOT + i] = f ? 1.f : 0.f;  // fg_mask
    out[(size_t)86 * N_TOT + i] = (float)m;       // target_gt_idx
    fgm_lblw[i] = f ? lbl : -1;
    mval_norm[i] = nrm;
}

// Kernel 4: coalesced one-thread-per-element scores write (86 MB).
__global__ __launch_bounds__(256) void k_scores(
    const int* __restrict__ lblw,
    const float* __restrict__ norm,
    float* __restrict__ out_scores) {
    int j = blockIdx.x * blockDim.x + threadIdx.x;
    if (j >= N_TOT * NC) return;
    int i = j / NC;
    int c = j - i * NC;
    out_scores[j] = (c == lblw[i]) ? norm[i] : 0.f;
}

extern "C" void kernel_launch(void* const* d_in, const int* in_sizes, int n_in,
                              void* d_out, int out_size, void* d_ws, size_t ws_size,
                              hipStream_t stream) {
    const float* pd_scores = (const float*)d_in[0];
    const float* pd_bboxes = (const float*)d_in[1];
    const float* anc       = (const float*)d_in[2];
    const int*   gt_labels = (const int*)d_in[3];
    // d_in[4] = gt_scores: unused by the reference
    const float* gt_bboxes = (const float*)d_in[5];
    const float* mask_gt   = (const float*)d_in[6];
    float* out = (float*)d_out;

    char* ws = (char*)d_ws;
    int*   fg        = (int*)ws;                          // N_TOT i32
    int*   assignm   = (int*)(ws + 4 * (size_t)N_TOT);    // N_TOT i32
    float* mval      = (float*)(ws + 8 * (size_t)N_TOT);  // N_TOT f32
    float* pos_align = (float*)(ws + 12 * (size_t)N_TOT); // BS*NM f32
    float* pos_ovl   = pos_align + BS * NM;               // BS*NM f32

    hipMemsetAsync(fg, 0, 4 * (size_t)N_TOT, stream);
    hipMemsetAsync(assignm, 0x7F, 4 * (size_t)N_TOT, stream);  // large sentinel
    hipMemsetAsync(pos_align, 0, 2 * 4 * (size_t)(BS * NM), stream);

    k_topk<<<BS * NM, 256, 0, stream>>>(pd_scores, pd_bboxes, anc, gt_labels,
                                        gt_bboxes, mask_gt, fg, assignm);

    int nb = (N_TOT + 255) / 256;
    k_assign<<<nb, 256, 0, stream>>>(pd_scores, pd_bboxes, anc, gt_labels,
                                     gt_bboxes, mask_gt, fg, assignm, mval,
                                     pos_align, pos_ovl);

    k_final<<<nb, 256, 0, stream>>>(gt_labels, gt_bboxes, fg, assignm, mval,
                                    pos_align, pos_ovl, out);

    int nb2 = (N_TOT * NC + 255) / 256;
    k_scores<<<nb2, 256, 0, stream>>>(fg, mval, out + (size_t)5 * N_TOT);
}

// Round 2
// 105.435 us; speedup vs baseline: 1.8701x; 1.8701x over previous
//
#include <hip/hip_runtime.h>
#include <math.h>

#define BS 32
#define NM 64
#define NA 8400
#define NC 80
#define TOPKK 13
#define N_TOT (BS * NA)

// CIoU (box1 = gt, box2 = pred), clipped at 0 — transcribed from the
// reference _ciou with eps=1e-7, then jnp.clip(x, 0).
__device__ __forceinline__ float ciou_clip(float gx1, float gy1, float gx2, float gy2,
                                           float px1, float py1, float px2, float py2) {
    const float eps = 1e-7f;
    float w1 = gx2 - gx1, h1 = gy2 - gy1 + eps;
    float w2 = px2 - px1, h2 = py2 - py1 + eps;
    float iw = fmaxf(fminf(gx2, px2) - fmaxf(gx1, px1), 0.f);
    float ih = fmaxf(fminf(gy2, py2) - fmaxf(gy1, py1), 0.f);
    float inter = iw * ih;
    float uni = w1 * h1 + w2 * h2 - inter + eps;
    float iou = inter / uni;
    float cw = fmaxf(gx2, px2) - fminf(gx1, px1);
    float ch = fmaxf(gy2, py2) - fminf(gy1, py1);
    float c2 = cw * cw + ch * ch + eps;
    float dx = px1 + px2 - gx1 - gx2;
    float dy = py1 + py2 - gy1 - gy2;
    float rho2 = (dx * dx + dy * dy) * 0.25f;
    float dat = atanf(w2 / h2) - atanf(w1 / h1);
    float v = 0.4052847345693511f * dat * dat;  // 4/pi^2
    float al = v / (v - iou + 1.0000001f);      // 1.0 + eps
    return fmaxf(iou - (rho2 / c2 + v * al), 0.f);
}

__device__ __forceinline__ unsigned long long umax64(unsigned long long a,
                                                     unsigned long long b) {
    return a > b ? a : b;
}
__device__ __forceinline__ unsigned long long umin64(unsigned long long a,
                                                     unsigned long long b) {
    return a < b ? a : b;
}

// Init kernel: one launch instead of 3 memsets.
__global__ __launch_bounds__(256) void k_init(int* __restrict__ fg,
                                              int* __restrict__ assignm,
                                              float* __restrict__ pos) {
    int i = blockIdx.x * blockDim.x + threadIdx.x;
    if (i < N_TOT) {
        fg[i] = 0;
        assignm[i] = 0x7FFFFFFF;
    }
    if (i < 2 * BS * NM) pos[i] = 0.f;
}

// Kernel 1: one block per (b, m). Single-pass per-thread top-13 in registers
// (u64 key = metric_bits<<32 | (NA-1-a)<<1 | in_gts), then 13 head-merge
// rounds (wave shfl_xor max + 4-way LDS merge). Key ordering reproduces
// jax.lax.top_k semantics: value desc, index asc on ties (validity bit sits
// below the unique index bits so it never decides the order).
__global__ __launch_bounds__(256) void k_topk(
    const float* __restrict__ pd_scores,
    const float* __restrict__ pd_bboxes,
    const float* __restrict__ anc,
    const int* __restrict__ gt_labels,
    const float* __restrict__ gt_bboxes,
    const float* __restrict__ mask_gt,
    int* __restrict__ fg,
    int* __restrict__ assignm) {
    const int bm = blockIdx.x;
    // mask_gt == 0: topk_idxs forced to 0 -> count=13 at idx0 -> mask_topk=0.
    if (mask_gt[bm] <= 0.f) return;

    const int tid = threadIdx.x;
    const int b = bm / NM;
    const int m = bm - b * NM;
    const float4 g = ((const float4*)gt_bboxes)[bm];
    const int lbl = gt_labels[bm];
    const float4* pb = (const float4*)(pd_bboxes + (size_t)b * NA * 4);
    const float* ps = pd_scores + (size_t)b * NA * NC + lbl;
    const float2* anc2 = (const float2*)anc;

    unsigned long long t[TOPKK];
#pragma unroll
    for (int i = 0; i < TOPKK; ++i) t[i] = 0ull;

    for (int a = tid; a < NA; a += 256) {
        float2 axy = anc2[a];
        float dmin = fminf(fminf(axy.x - g.x, axy.y - g.y),
                           fminf(g.z - axy.x, g.w - axy.y));
        bool valid = dmin > 1e-9f;  // EPS = 1e-9
        float metric = 0.f;
        if (valid) {
            float4 p = pb[a];
            float ov = ciou_clip(g.x, g.y, g.z, g.w, p.x, p.y, p.z, p.w);
            float s = ps[(size_t)a * NC];
            float ov2 = ov * ov;
            metric = s * ov2 * ov2 * ov2;  // score^1 * overlap^6
        }
        unsigned long long key =
            ((unsigned long long)__float_as_uint(metric) << 32) |
            ((unsigned)(NA - 1 - a) << 1) | (valid ? 1u : 0u);
        if (key > t[TOPKK - 1]) {
#pragma unroll
            for (int i = 0; i < TOPKK; ++i) {  // static-index insert
                unsigned long long lo = umin64(t[i], key);
                t[i] = umax64(t[i], key);
                key = lo;
            }
        }
    }

    __shared__ unsigned long long wmax[4];
    const int lane = tid & 63, wid = tid >> 6;

    for (int k = 0; k < TOPKK; ++k) {
        unsigned long long key = t[0];
#pragma unroll
        for (int off = 32; off > 0; off >>= 1)
            key = umax64(key, __shfl_xor(key, off, 64));
        if (lane == 0) wmax[wid] = key;
        __syncthreads();
        unsigned long long gmax =
            umax64(umax64(wmax[0], wmax[1]), umax64(wmax[2], wmax[3]));
        __syncthreads();  // wmax reused next round
        if (t[0] == gmax) {  // keys unique: exactly one owner
#pragma unroll
            for (int i = 0; i < TOPKK - 1; ++i) t[i] = t[i + 1];
            t[TOPKK - 1] = 0ull;
            if (gmax & 1ull) {  // mask_in_gts filter
                int a = NA - 1 - (int)((gmax >> 1) & 0x3FFFull);
                atomicAdd(&fg[b * NA + a], 1);
                atomicMin(&assignm[b * NA + a], m);
            }
        }
    }
}

// Kernel 2: one thread per (b, a). Resolve multi-assignment via masked-overlap
// argmax (tie -> lowest m, matching jnp.argmax), recompute assigned
// metric/overlap, reduce pos_align/pos_ovl per (b, m).
__global__ __launch_bounds__(256) void k_assign(
    const float* __restrict__ pd_scores,
    const float* __restrict__ pd_bboxes,
    const float* __restrict__ anc,
    const int* __restrict__ gt_labels,
    const float* __restrict__ gt_bboxes,
    const float* __restrict__ mask_gt,
    int* fg_inout,      // in: candidate count; out: fg flag (0/1)
    int* assign_inout,  // in: min-m candidate; out: final target gt idx
    float* __restrict__ mval,
    float* __restrict__ pos_align,
    float* __restrict__ pos_ovl) {
    int i = blockIdx.x * blockDim.x + threadIdx.x;
    if (i >= N_TOT) return;
    int b = i / NA, a = i - b * NA;

    int f = fg_inout[i];
    if (f <= 0) {
        fg_inout[i] = 0;
        assign_inout[i] = 0;  // argmax of all-zero column = 0
        mval[i] = 0.f;
        return;
    }

    float ax = anc[2 * a], ay = anc[2 * a + 1];
    float4 p = ((const float4*)pd_bboxes)[i];

    int m;
    if (f == 1) {
        m = assign_inout[i];
    } else {
        // multi: one_hot(argmax_m overlaps[b,:,a]); ties -> first m
        float best = -1.f;
        int bestm = 0;
        for (int mm = 0; mm < NM; ++mm) {
            float4 gg = ((const float4*)gt_bboxes)[b * NM + mm];
            float dmin = fminf(fminf(ax - gg.x, ay - gg.y),
                               fminf(gg.z - ax, gg.w - ay));
            float ov = 0.f;
            if (dmin > 1e-9f && mask_gt[b * NM + mm] > 0.f)
                ov = ciou_clip(gg.x, gg.y, gg.z, gg.w, p.x, p.y, p.z, p.w);
            if (ov > best) { best = ov; bestm = mm; }
        }
        m = bestm;
    }

    float4 gg = ((const float4*)gt_bboxes)[b * NM + m];
    float dmin = fminf(fminf(ax - gg.x, ay - gg.y), fminf(gg.z - ax, gg.w - ay));
    float mv = 0.f, ovv = 0.f;
    if (dmin > 1e-9f && mask_gt[b * NM + m] > 0.f) {
        ovv = ciou_clip(gg.x, gg.y, gg.z, gg.w, p.x, p.y, p.z, p.w);
        float s = pd_scores[(size_t)i * NC + gt_labels[b * NM + m]];
        float ov2 = ovv * ovv;
        mv = s * ov2 * ov2 * ov2;
    }

    fg_inout[i] = 1;
    assign_inout[i] = m;
    mval[i] = mv;
    // values >= 0 -> int compare == float compare; order-independent.
    atomicMax((int*)&pos_align[b * NM + m], __float_as_int(mv));
    atomicMax((int*)&pos_ovl[b * NM + m], __float_as_int(ovv));
}

// Kernel 3: per-anchor finalize.
__global__ __launch_bounds__(256) void k_final(
    const int* __restrict__ gt_labels,
    const float* __restrict__ gt_bboxes,
    int* fgm_lblw,    // in: fg flag; out: label if fg else -1
    const int* __restrict__ tgt,
    float* mval_norm, // in: metric val; out: norm
    const float* __restrict__ pos_align,
    const float* __restrict__ pos_ovl,
    float* __restrict__ out) {
    int i = blockIdx.x * blockDim.x + threadIdx.x;
    if (i >= N_TOT) return;
    int b = i / NA;
    int m = tgt[i];
    int f = fgm_lblw[i];
    int lbl = gt_labels[b * NM + m];
    lbl = lbl < 0 ? 0 : lbl;
    float4 box = ((const float4*)gt_bboxes)[b * NM + m];
    float nrm = 0.f;
    if (f) nrm = mval_norm[i] * pos_ovl[b * NM + m] / (pos_align[b * NM + m] + 1e-9f);

    out[i] = (float)lbl;                          // target_labels
    ((float4*)(out + N_TOT))[i] = box;            // target_bboxes
    out[(size_t)85 * N_TOT + i] = f ? 1.f : 0.f;  // fg_mask
    out[(size_t)86 * N_TOT + i] = (float)m;       // target_gt_idx
    fgm_lblw[i] = f ? lbl : -1;
    mval_norm[i] = nrm;
}

// Kernel 4: float4-vectorized scores write (86 MB, the HBM floor).
__global__ __launch_bounds__(256) void k_scores(
    const int* __restrict__ lblw,
    const float* __restrict__ norm,
    float4* __restrict__ out_scores) {
    int j = blockIdx.x * blockDim.x + threadIdx.x;  // one float4 per thread
    if (j >= N_TOT * (NC / 4)) return;
    int i = j / (NC / 4);
    int c0 = (j - i * (NC / 4)) * 4;
    int lbl = lblw[i];
    float4 v = make_float4(0.f, 0.f, 0.f, 0.f);
    if (lbl >= c0 && lbl < c0 + 4) {
        float n = norm[i];
        if (lbl == c0) v.x = n;
        else if (lbl == c0 + 1) v.y = n;
        else if (lbl == c0 + 2) v.z = n;
        else v.w = n;
    }
    out_scores[j] = v;
}

extern "C" void kernel_launch(void* const* d_in, const int* in_sizes, int n_in,
                              void* d_out, int out_size, void* d_ws, size_t ws_size,
                              hipStream_t stream) {
    const float* pd_scores = (const float*)d_in[0];
    const float* pd_bboxes = (const float*)d_in[1];
    const float* anc       = (const float*)d_in[2];
    const int*   gt_labels = (const int*)d_in[3];
    // d_in[4] = gt_scores: unused by the reference
    const float* gt_bboxes = (const float*)d_in[5];
    const float* mask_gt   = (const float*)d_in[6];
    float* out = (float*)d_out;

    char* ws = (char*)d_ws;
    int*   fg        = (int*)ws;                          // N_TOT i32
    int*   assignm   = (int*)(ws + 4 * (size_t)N_TOT);    // N_TOT i32
    float* mval      = (float*)(ws + 8 * (size_t)N_TOT);  // N_TOT f32
    float* pos_align = (float*)(ws + 12 * (size_t)N_TOT); // BS*NM f32
    float* pos_ovl   = pos_align + BS * NM;               // BS*NM f32

    int nb = (N_TOT + 255) / 256;
    k_init<<<nb, 256, 0, stream>>>(fg, assignm, pos_align);

    k_topk<<<BS * NM, 256, 0, stream>>>(pd_scores, pd_bboxes, anc, gt_labels,
                                        gt_bboxes, mask_gt, fg, assignm);

    k_assign<<<nb, 256, 0, stream>>>(pd_scores, pd_bboxes, anc, gt_labels,
                                     gt_bboxes, mask_gt, fg, assignm, mval,
                                     pos_align, pos_ovl);

    k_final<<<nb, 256, 0, stream>>>(gt_labels, gt_bboxes, fg, assignm, mval,
                                    pos_align, pos_ovl, out);

    int nb2 = (N_TOT * (NC / 4) + 255) / 256;
    k_scores<<<nb2, 256, 0, stream>>>(fg, mval, (float4*)(out + (size_t)5 * N_TOT));
}

// Round 3
// 90.740 us; speedup vs baseline: 2.1729x; 1.1619x over previous
//
#include <hip/hip_runtime.h>
#include <math.h>

#define BS 32
#define NM 64
#define NA 8400
#define NC 80
#define TOPKK 13
#define N_TOT (BS * NA)

// CIoU (box1 = gt, box2 = pred), clipped at 0 — transcribed from the
// reference _ciou with eps=1e-7, then jnp.clip(x, 0).
__device__ __forceinline__ float ciou_clip(float gx1, float gy1, float gx2, float gy2,
                                           float px1, float py1, float px2, float py2) {
    const float eps = 1e-7f;
    float w1 = gx2 - gx1, h1 = gy2 - gy1 + eps;
    float w2 = px2 - px1, h2 = py2 - py1 + eps;
    float iw = fmaxf(fminf(gx2, px2) - fmaxf(gx1, px1), 0.f);
    float ih = fmaxf(fminf(gy2, py2) - fmaxf(gy1, py1), 0.f);
    float inter = iw * ih;
    float uni = w1 * h1 + w2 * h2 - inter + eps;
    float iou = inter / uni;
    float cw = fmaxf(gx2, px2) - fminf(gx1, px1);
    float ch = fmaxf(gy2, py2) - fminf(gy1, py1);
    float c2 = cw * cw + ch * ch + eps;
    float dx = px1 + px2 - gx1 - gx2;
    float dy = py1 + py2 - gy1 - gy2;
    float rho2 = (dx * dx + dy * dy) * 0.25f;
    float dat = atanf(w2 / h2) - atanf(w1 / h1);
    float v = 0.4052847345693511f * dat * dat;  // 4/pi^2
    float al = v / (v - iou + 1.0000001f);      // 1.0 + eps
    return fmaxf(iou - (rho2 / c2 + v * al), 0.f);
}

__device__ __forceinline__ unsigned long long umax64(unsigned long long a,
                                                     unsigned long long b) {
    return a > b ? a : b;
}
__device__ __forceinline__ unsigned long long umin64(unsigned long long a,
                                                     unsigned long long b) {
    return a < b ? a : b;
}

// anchor index -> (ax, ay) computed exactly: (i+0.5)*stride, stride = 2^k,
// bit-identical to the reference's (arange(n)+0.5)*s in f32.
__device__ __forceinline__ void anchor_xy(int a, float& ax, float& ay) {
    int loc, n; float s;
    if (a < 6400)      { loc = a;        n = 80; s = 8.f;  }
    else if (a < 8000) { loc = a - 6400; n = 40; s = 16.f; }
    else               { loc = a - 8000; n = 20; s = 32.f; }
    int row = loc / n, col = loc - row * n;
    ax = ((float)col + 0.5f) * s;
    ay = ((float)row + 0.5f) * s;
}

__global__ __launch_bounds__(256) void k_init(int* __restrict__ fg,
                                              int* __restrict__ assignm,
                                              float* __restrict__ pos) {
    int i = blockIdx.x * blockDim.x + threadIdx.x;
    if (i < N_TOT) {
        fg[i] = 0;
        assignm[i] = 0x7FFFFFFF;
    }
    if (i < 2 * BS * NM) pos[i] = 0.f;
}

// Kernel 1: one SINGLE-WAVE block per (b, m). Enumerate only the anchors in
// the (±1-widened) grid rectangle of the gt box per stride level (~380 of
// 8400), exact dmin test preserves reference semantics. Per-lane top-13 in
// registers, then <=13 barrier-free shfl-butterfly pop rounds. Zero-metric
// filler slots (reference top_k picks smallest-index zero-metric anchors)
// resolved exactly via a 64-lane ballot over anchors 0..63.
__global__ __launch_bounds__(64) void k_topk(
    const float* __restrict__ pd_scores,
    const float* __restrict__ pd_bboxes,
    const int* __restrict__ gt_labels,
    const float* __restrict__ gt_bboxes,
    const float* __restrict__ mask_gt,
    int* __restrict__ fg,
    int* __restrict__ assignm) {
    const int bm = blockIdx.x;
    if (mask_gt[bm] <= 0.f) return;  // row contributes nothing (count=13@idx0)

    const int lane = threadIdx.x;
    const int b = bm / NM;
    const int m = bm - b * NM;
    const float4 g = ((const float4*)gt_bboxes)[bm];
    const int lbl = gt_labels[bm];
    const float4* pb = (const float4*)(pd_bboxes + (size_t)b * NA * 4);
    const float* ps = pd_scores + (size_t)b * NA * NC + lbl;

    // per-level candidate rects (widened +-1; exact test filters)
    int c0_0, r0_0, w_0, cnt_0, c0_1, r0_1, w_1, cnt_1, c0_2, r0_2, w_2, cnt_2;
    float iw_0, iw_1, iw_2;  // 1/w for fast row/col split
    {
#define MKRECT(L, NN, SS, C0, R0, W, CNT, IW)                                  \
        {                                                                      \
            int c0 = (int)floorf(g.x / SS - 0.5f) - 1; if (c0 < 0) c0 = 0;     \
            int c1 = (int)ceilf (g.z / SS - 0.5f) + 1; if (c1 > NN - 1) c1 = NN - 1; \
            int r0 = (int)floorf(g.y / SS - 0.5f) - 1; if (r0 < 0) r0 = 0;     \
            int r1 = (int)ceilf (g.w / SS - 0.5f) + 1; if (r1 > NN - 1) r1 = NN - 1; \
            int w = c1 - c0 + 1; if (w < 0) w = 0;                             \
            int h = r1 - r0 + 1; if (h < 0) h = 0;                             \
            C0 = c0; R0 = r0; W = w; CNT = w * h; IW = w > 0 ? 1.f / (float)w : 0.f; \
        }
        MKRECT(0, 80, 8.f,  c0_0, r0_0, w_0, cnt_0, iw_0)
        MKRECT(1, 40, 16.f, c0_1, r0_1, w_1, cnt_1, iw_1)
        MKRECT(2, 20, 32.f, c0_2, r0_2, w_2, cnt_2, iw_2)
#undef MKRECT
    }
    const int tot01 = cnt_0 + cnt_1;
    const int total = tot01 + cnt_2;

    unsigned long long t[TOPKK];
#pragma unroll
    for (int i = 0; i < TOPKK; ++i) t[i] = 0ull;

    for (int j = lane; j < total; j += 64) {
        int local, c0, r0, w, base, n; float s, iw;
        if (j < cnt_0)      { local = j;         c0 = c0_0; r0 = r0_0; w = w_0; base = 0;    n = 80; s = 8.f;  iw = iw_0; }
        else if (j < tot01) { local = j - cnt_0; c0 = c0_1; r0 = r0_1; w = w_1; base = 6400; n = 40; s = 16.f; iw = iw_1; }
        else                { local = j - tot01; c0 = c0_2; r0 = r0_2; w = w_2; base = 8000; n = 20; s = 32.f; iw = iw_2; }
        int rr = (int)(((float)local + 0.5f) * iw);  // exact for local<2^24, w<=82
        int cc = local - rr * w;
        int row = r0 + rr, col = c0 + cc;
        float ax = ((float)col + 0.5f) * s;
        float ay = ((float)row + 0.5f) * s;
        float dmin = fminf(fminf(ax - g.x, ay - g.y), fminf(g.z - ax, g.w - ay));
        if (dmin > 1e-9f) {  // exact mask_in_gts (EPS = 1e-9)
            int a = base + row * n + col;
            float4 p = pb[a];
            float ov = ciou_clip(g.x, g.y, g.z, g.w, p.x, p.y, p.z, p.w);
            float sc = ps[(size_t)a * NC];
            float ov2 = ov * ov;
            float metric = sc * ov2 * ov2 * ov2;  // score^1 * overlap^6
            unsigned long long key =
                ((unsigned long long)__float_as_uint(metric) << 32) |
                (unsigned)(NA - 1 - a);
            if (key > t[TOPKK - 1]) {
#pragma unroll
                for (int i = 0; i < TOPKK; ++i) {  // static-index sorted insert
                    unsigned long long lo = umin64(t[i], key);
                    t[i] = umax64(t[i], key);
                    key = lo;
                }
            }
        }
    }

    // pop positive-metric winners (value desc, index asc == jax.lax.top_k)
    int npos = 0;
#pragma unroll 1
    for (int k = 0; k < TOPKK; ++k) {
        unsigned long long key = t[0];
#pragma unroll
        for (int off = 32; off > 0; off >>= 1)
            key = umax64(key, __shfl_xor(key, off, 64));
        if ((key >> 32) == 0ull) break;  // no positives left
        ++npos;
        if (t[0] == key) {  // unique owner
            int a = NA - 1 - (int)(key & 0xFFFFFFFFull);
            atomicAdd(&fg[b * NA + a], 1);
            atomicMin(&assignm[b * NA + a], m);
#pragma unroll
            for (int i = 0; i < TOPKK - 1; ++i) t[i] = t[i + 1];
            t[TOPKK - 1] = 0ull;
        }
    }

    // fillers: remaining 13-npos slots go to the smallest-index zero-metric
    // anchors (reference top_k over mostly-zero row). They lie in indices
    // 0..25 <= 63. In-box fillers scatter; out-of-box are masked anyway.
    int nf = TOPKK - npos;
    if (nf > 0) {
        int f = lane;  // anchor f: level-0 row 0 -> ax=(f+0.5)*8, ay=4
        float ax = ((float)f + 0.5f) * 8.f, ay = 4.0f;
        float dmin = fminf(fminf(ax - g.x, ay - g.y), fminf(g.z - ax, g.w - ay));
        bool inbox = dmin > 1e-9f;
        float metric = 0.f;
        if (inbox) {
            float4 p = pb[f];
            float ov = ciou_clip(g.x, g.y, g.z, g.w, p.x, p.y, p.z, p.w);
            float ov2 = ov * ov;
            metric = ps[(size_t)f * NC] * ov2 * ov2 * ov2;
        }
        bool pos = inbox && (metric > 0.f);
        unsigned long long pmask = __ballot(pos);
        if (inbox && !pos) {
            int rank = __popcll(~pmask & ((1ull << f) - 1ull));
            if (rank < nf) {
                atomicAdd(&fg[b * NA + f], 1);
                atomicMin(&assignm[b * NA + f], m);
            }
        }
    }
}

// Kernel 2: one thread per (b, a). Resolve multi-assignment via masked-overlap
// argmax (tie -> lowest m, matching jnp.argmax), recompute assigned
// metric/overlap, reduce pos_align/pos_ovl per (b, m).
__global__ __launch_bounds__(256) void k_assign(
    const float* __restrict__ pd_scores,
    const float* __restrict__ pd_bboxes,
    const int* __restrict__ gt_labels,
    const float* __restrict__ gt_bboxes,
    const float* __restrict__ mask_gt,
    int* fg_inout,      // in: candidate count; out: fg flag (0/1)
    int* assign_inout,  // in: min-m candidate; out: final target gt idx
    float* __restrict__ mval,
    float* __restrict__ pos_align,
    float* __restrict__ pos_ovl) {
    int i = blockIdx.x * blockDim.x + threadIdx.x;
    if (i >= N_TOT) return;
    int b = i / NA, a = i - b * NA;

    int f = fg_inout[i];
    if (f <= 0) {
        fg_inout[i] = 0;
        assign_inout[i] = 0;  // argmax of all-zero column = 0
        mval[i] = 0.f;
        return;
    }

    float ax, ay;
    anchor_xy(a, ax, ay);
    float4 p = ((const float4*)pd_bboxes)[i];

    int m;
    if (f == 1) {
        m = assign_inout[i];
    } else {
        // multi: one_hot(argmax_m overlaps[b,:,a]); ties -> first m
        float best = -1.f;
        int bestm = 0;
        for (int mm = 0; mm < NM; ++mm) {
            float4 gg = ((const float4*)gt_bboxes)[b * NM + mm];
            float dmin = fminf(fminf(ax - gg.x, ay - gg.y),
                               fminf(gg.z - ax, gg.w - ay));
            float ov = 0.f;
            if (dmin > 1e-9f && mask_gt[b * NM + mm] > 0.f)
                ov = ciou_clip(gg.x, gg.y, gg.z, gg.w, p.x, p.y, p.z, p.w);
            if (ov > best) { best = ov; bestm = mm; }
        }
        m = bestm;
    }

    float4 gg = ((const float4*)gt_bboxes)[b * NM + m];
    float dmin = fminf(fminf(ax - gg.x, ay - gg.y), fminf(gg.z - ax, gg.w - ay));
    float mv = 0.f, ovv = 0.f;
    if (dmin > 1e-9f && mask_gt[b * NM + m] > 0.f) {
        ovv = ciou_clip(gg.x, gg.y, gg.z, gg.w, p.x, p.y, p.z, p.w);
        float s = pd_scores[(size_t)i * NC + gt_labels[b * NM + m]];
        float ov2 = ovv * ovv;
        mv = s * ov2 * ov2 * ov2;
    }

    fg_inout[i] = 1;
    assign_inout[i] = m;
    mval[i] = mv;
    // values >= 0 -> int compare == float compare; order-independent.
    atomicMax((int*)&pos_align[b * NM + m], __float_as_int(mv));
    atomicMax((int*)&pos_ovl[b * NM + m], __float_as_int(ovv));
}

// Kernel 3: per-anchor finalize.
__global__ __launch_bounds__(256) void k_final(
    const int* __restrict__ gt_labels,
    const float* __restrict__ gt_bboxes,
    int* fgm_lblw,    // in: fg flag; out: label if fg else -1
    const int* __restrict__ tgt,
    float* mval_norm, // in: metric val; out: norm
    const float* __restrict__ pos_align,
    const float* __restrict__ pos_ovl,
    float* __restrict__ out) {
    int i = blockIdx.x * blockDim.x + threadIdx.x;
    if (i >= N_TOT) return;
    int b = i / NA;
    int m = tgt[i];
    int f = fgm_lblw[i];
    int lbl = gt_labels[b * NM + m];
    lbl = lbl < 0 ? 0 : lbl;
    float4 box = ((const float4*)gt_bboxes)[b * NM + m];
    float nrm = 0.f;
    if (f) nrm = mval_norm[i] * pos_ovl[b * NM + m] / (pos_align[b * NM + m] + 1e-9f);

    out[i] = (float)lbl;                          // target_labels
    ((float4*)(out + N_TOT))[i] = box;            // target_bboxes
    out[(size_t)85 * N_TOT + i] = f ? 1.f : 0.f;  // fg_mask
    out[(size_t)86 * N_TOT + i] = (float)m;       // target_gt_idx
    fgm_lblw[i] = f ? lbl : -1;
    mval_norm[i] = nrm;
}

// Kernel 4: float4-vectorized scores write (86 MB, the HBM floor).
__global__ __launch_bounds__(256) void k_scores(
    const int* __restrict__ lblw,
    const float* __restrict__ norm,
    float4* __restrict__ out_scores) {
    int j = blockIdx.x * blockDim.x + threadIdx.x;  // one float4 per thread
    if (j >= N_TOT * (NC / 4)) return;
    int i = j / (NC / 4);
    int c0 = (j - i * (NC / 4)) * 4;
    int lbl = lblw[i];
    float4 v = make_float4(0.f, 0.f, 0.f, 0.f);
    if (lbl >= c0 && lbl < c0 + 4) {
        float n = norm[i];
        if (lbl == c0) v.x = n;
        else if (lbl == c0 + 1) v.y = n;
        else if (lbl == c0 + 2) v.z = n;
        else v.w = n;
    }
    out_scores[j] = v;
}

extern "C" void kernel_launch(void* const* d_in, const int* in_sizes, int n_in,
                              void* d_out, int out_size, void* d_ws, size_t ws_size,
                              hipStream_t stream) {
    const float* pd_scores = (const float*)d_in[0];
    const float* pd_bboxes = (const float*)d_in[1];
    const int*   gt_labels = (const int*)d_in[3];
    // d_in[2] = anc_points (recomputed in-register), d_in[4] = gt_scores: unused
    const float* gt_bboxes = (const float*)d_in[5];
    const float* mask_gt   = (const float*)d_in[6];
    float* out = (float*)d_out;

    char* ws = (char*)d_ws;
    int*   fg        = (int*)ws;                          // N_TOT i32
    int*   assignm   = (int*)(ws + 4 * (size_t)N_TOT);    // N_TOT i32
    float* mval      = (float*)(ws + 8 * (size_t)N_TOT);  // N_TOT f32
    float* pos_align = (float*)(ws + 12 * (size_t)N_TOT); // BS*NM f32
    float* pos_ovl   = pos_align + BS * NM;               // BS*NM f32

    int nb = (N_TOT + 255) / 256;
    k_init<<<nb, 256, 0, stream>>>(fg, assignm, pos_align);

    k_topk<<<BS * NM, 64, 0, stream>>>(pd_scores, pd_bboxes, gt_labels,
                                       gt_bboxes, mask_gt, fg, assignm);

    k_assign<<<nb, 256, 0, stream>>>(pd_scores, pd_bboxes, gt_labels,
                                     gt_bboxes, mask_gt, fg, assignm, mval,
                                     pos_align, pos_ovl);

    k_final<<<nb, 256, 0, stream>>>(gt_labels, gt_bboxes, fg, assignm, mval,
                                    pos_align, pos_ovl, out);

    int nb2 = (N_TOT * (NC / 4) + 255) / 256;
    k_scores<<<nb2, 256, 0, stream>>>(fg, mval, (float4*)(out + (size_t)5 * N_TOT));
}

// Round 4
// 85.930 us; speedup vs baseline: 2.2946x; 1.0560x over previous
//
#include <hip/hip_runtime.h>
#include <math.h>

#define BS 32
#define NM 64
#define NA 8400
#define NC 80
#define TOPKK 13
#define N_TOT (BS * NA)

// CIoU (box1 = gt, box2 = pred), clipped at 0 — transcribed from the
// reference _ciou with eps=1e-7, then jnp.clip(x, 0).
__device__ __forceinline__ float ciou_clip(float gx1, float gy1, float gx2, float gy2,
                                           float px1, float py1, float px2, float py2) {
    const float eps = 1e-7f;
    float w1 = gx2 - gx1, h1 = gy2 - gy1 + eps;
    float w2 = px2 - px1, h2 = py2 - py1 + eps;
    float iw = fmaxf(fminf(gx2, px2) - fmaxf(gx1, px1), 0.f);
    float ih = fmaxf(fminf(gy2, py2) - fmaxf(gy1, py1), 0.f);
    float inter = iw * ih;
    float uni = w1 * h1 + w2 * h2 - inter + eps;
    float iou = inter / uni;
    float cw = fmaxf(gx2, px2) - fminf(gx1, px1);
    float ch = fmaxf(gy2, py2) - fminf(gy1, py1);
    float c2 = cw * cw + ch * ch + eps;
    float dx = px1 + px2 - gx1 - gx2;
    float dy = py1 + py2 - gy1 - gy2;
    float rho2 = (dx * dx + dy * dy) * 0.25f;
    float dat = atanf(w2 / h2) - atanf(w1 / h1);
    float v = 0.4052847345693511f * dat * dat;  // 4/pi^2
    float al = v / (v - iou + 1.0000001f);      // 1.0 + eps
    return fmaxf(iou - (rho2 / c2 + v * al), 0.f);
}

__device__ __forceinline__ unsigned long long umax64(unsigned long long a,
                                                     unsigned long long b) {
    return a > b ? a : b;
}
__device__ __forceinline__ unsigned long long umin64(unsigned long long a,
                                                     unsigned long long b) {
    return a < b ? a : b;
}

// anchor index -> (ax, ay) exactly: (i+0.5)*stride, bit-identical to reference.
__device__ __forceinline__ void anchor_xy(int a, float& ax, float& ay) {
    int loc, n; float s;
    if (a < 6400)      { loc = a;        n = 80; s = 8.f;  }
    else if (a < 8000) { loc = a - 6400; n = 40; s = 16.f; }
    else               { loc = a - 8000; n = 20; s = 32.f; }
    int row = loc / n, col = loc - row * n;
    ax = ((float)col + 0.5f) * s;
    ay = ((float)row + 0.5f) * s;
}

__global__ __launch_bounds__(256) void k_init(int* __restrict__ fg,
                                              int* __restrict__ assignm,
                                              float* __restrict__ pos) {
    int i = blockIdx.x * blockDim.x + threadIdx.x;
    if (i < N_TOT) {
        fg[i] = 0;
        assignm[i] = 0x7FFFFFFF;
    }
    if (i < 2 * BS * NM) pos[i] = 0.f;
}

// Kernel 1: one 256-thread block per (b, m) — 4 waves for latency hiding.
// Rect-enumerated candidates (~380 of 8400), per-lane top-13 in registers,
// per-wave barrier-free butterfly pop of 13, then one barrier and wave 0
// merges the 4x13 keys and scatters. Filler slots (reference top_k picks
// smallest-index zero-metric anchors) resolved exactly via 64-lane ballot.
__global__ __launch_bounds__(256) void k_topk(
    const float* __restrict__ pd_scores,
    const float* __restrict__ pd_bboxes,
    const int* __restrict__ gt_labels,
    const float* __restrict__ gt_bboxes,
    const float* __restrict__ mask_gt,
    int* __restrict__ fg,
    int* __restrict__ assignm) {
    // XCD-aware swizzle (bijective: 2048 % 8 == 0): blocks sharing batch b's
    // score/bbox panels land on the same XCD's L2.
    const int bm = ((blockIdx.x & 7) << 8) | (blockIdx.x >> 3);
    if (mask_gt[bm] <= 0.f) return;  // row contributes nothing (count=13@idx0)

    const int tid = threadIdx.x;
    const int lane = tid & 63, wid = tid >> 6;
    const int b = bm / NM;
    const int m = bm - b * NM;
    const float4 g = ((const float4*)gt_bboxes)[bm];
    const int lbl = gt_labels[bm];
    const float4* pb = (const float4*)(pd_bboxes + (size_t)b * NA * 4);
    const float* ps = pd_scores + (size_t)b * NA * NC + lbl;

    // per-level candidate rects (widened +-1; exact dmin test filters)
    int c0_0, r0_0, w_0, cnt_0, c0_1, r0_1, w_1, cnt_1, c0_2, r0_2, w_2, cnt_2;
    float iw_0, iw_1, iw_2;
    {
#define MKRECT(NN, SS, C0, R0, W, CNT, IW)                                     \
        {                                                                      \
            int c0 = (int)floorf(g.x / SS - 0.5f) - 1; if (c0 < 0) c0 = 0;     \
            int c1 = (int)ceilf (g.z / SS - 0.5f) + 1; if (c1 > NN - 1) c1 = NN - 1; \
            int r0 = (int)floorf(g.y / SS - 0.5f) - 1; if (r0 < 0) r0 = 0;     \
            int r1 = (int)ceilf (g.w / SS - 0.5f) + 1; if (r1 > NN - 1) r1 = NN - 1; \
            int w = c1 - c0 + 1; if (w < 0) w = 0;                             \
            int h = r1 - r0 + 1; if (h < 0) h = 0;                             \
            C0 = c0; R0 = r0; W = w; CNT = w * h; IW = w > 0 ? 1.f / (float)w : 0.f; \
        }
        MKRECT(80, 8.f,  c0_0, r0_0, w_0, cnt_0, iw_0)
        MKRECT(40, 16.f, c0_1, r0_1, w_1, cnt_1, iw_1)
        MKRECT(20, 32.f, c0_2, r0_2, w_2, cnt_2, iw_2)
#undef MKRECT
    }
    const int tot01 = cnt_0 + cnt_1;
    const int total = tot01 + cnt_2;

    unsigned long long t[TOPKK];
#pragma unroll
    for (int i = 0; i < TOPKK; ++i) t[i] = 0ull;

    for (int j = tid; j < total; j += 256) {
        int local, c0, r0, w, base, n; float s, iw;
        if (j < cnt_0)      { local = j;         c0 = c0_0; r0 = r0_0; w = w_0; base = 0;    n = 80; s = 8.f;  iw = iw_0; }
        else if (j < tot01) { local = j - cnt_0; c0 = c0_1; r0 = r0_1; w = w_1; base = 6400; n = 40; s = 16.f; iw = iw_1; }
        else                { local = j - tot01; c0 = c0_2; r0 = r0_2; w = w_2; base = 8000; n = 20; s = 32.f; iw = iw_2; }
        int rr = (int)(((float)local + 0.5f) * iw);  // exact for w<=82
        int cc = local - rr * w;
        int row = r0 + rr, col = c0 + cc;
        float ax = ((float)col + 0.5f) * s;
        float ay = ((float)row + 0.5f) * s;
        float dmin = fminf(fminf(ax - g.x, ay - g.y), fminf(g.z - ax, g.w - ay));
        if (dmin > 1e-9f) {  // exact mask_in_gts (EPS = 1e-9)
            int a = base + row * n + col;
            float4 p = pb[a];
            float ov = ciou_clip(g.x, g.y, g.z, g.w, p.x, p.y, p.z, p.w);
            float sc = ps[(size_t)a * NC];
            float ov2 = ov * ov;
            float metric = sc * ov2 * ov2 * ov2;  // score^1 * overlap^6
            unsigned long long key =
                ((unsigned long long)__float_as_uint(metric) << 32) |
                (unsigned)(NA - 1 - a);
            if (key > t[TOPKK - 1]) {
#pragma unroll
                for (int i = 0; i < TOPKK; ++i) {  // static-index sorted insert
                    unsigned long long lo = umin64(t[i], key);
                    t[i] = umax64(t[i], key);
                    key = lo;
                }
            }
        }
    }

    // per-wave pop of its own top-13 (barrier-free), keys to LDS
    __shared__ unsigned long long smerge[4 * TOPKK];
#pragma unroll 1
    for (int k = 0; k < TOPKK; ++k) {
        unsigned long long key = t[0];
#pragma unroll
        for (int off = 32; off > 0; off >>= 1)
            key = umax64(key, __shfl_xor(key, off, 64));
        if (lane == 0) smerge[wid * TOPKK + k] = key;
        if (t[0] == key && key != 0ull) {  // unique owner pops
#pragma unroll
            for (int i = 0; i < TOPKK - 1; ++i) t[i] = t[i + 1];
            t[TOPKK - 1] = 0ull;
        }
    }
    __syncthreads();

    if (wid != 0) return;

    // wave 0: merge 52 keys, pop global top-13, scatter
    unsigned long long key = (lane < 4 * TOPKK) ? smerge[lane] : 0ull;
    int npos = 0;
#pragma unroll 1
    for (int k = 0; k < TOPKK; ++k) {
        unsigned long long gmax = key;
#pragma unroll
        for (int off = 32; off > 0; off >>= 1)
            gmax = umax64(gmax, __shfl_xor(gmax, off, 64));
        if ((gmax >> 32) == 0ull) break;  // no positives left
        ++npos;
        if (key == gmax) {  // unique owner
            int a = NA - 1 - (int)(key & 0xFFFFFFFFull);
            atomicAdd(&fg[b * NA + a], 1);
            atomicMin(&assignm[b * NA + a], m);
            key = 0ull;
        }
    }

    // fillers: remaining 13-npos slots = smallest-index zero-metric anchors
    // (they provably lie in indices 0..25 <= 63). In-box fillers scatter;
    // out-of-box are masked by mask_in_gts downstream anyway.
    int nf = TOPKK - npos;
    if (nf > 0) {
        int f = lane;  // anchor f: level-0 row 0 -> ax=(f+0.5)*8, ay=4
        float ax = ((float)f + 0.5f) * 8.f, ay = 4.0f;
        float dmin = fminf(fminf(ax - g.x, ay - g.y), fminf(g.z - ax, g.w - ay));
        bool inbox = dmin > 1e-9f;
        float metric = 0.f;
        if (inbox) {
            float4 p = pb[f];
            float ov = ciou_clip(g.x, g.y, g.z, g.w, p.x, p.y, p.z, p.w);
            float ov2 = ov * ov;
            metric = ps[(size_t)f * NC] * ov2 * ov2 * ov2;
        }
        bool pos = inbox && (metric > 0.f);
        unsigned long long pmask = __ballot(pos);
        if (inbox && !pos) {
            int rank = __popcll(~pmask & ((1ull << f) - 1ull));
            if (rank < nf) {
                atomicAdd(&fg[b * NA + f], 1);
                atomicMin(&assignm[b * NA + f], m);
            }
        }
    }
}

// Kernel 2: one thread per (b, a). Resolve multi-assignment via masked-overlap
// argmax (tie -> lowest m), recompute assigned metric/overlap, reduce
// pos_align/pos_ovl per (b, m).
__global__ __launch_bounds__(256) void k_assign(
    const float* __restrict__ pd_scores,
    const float* __restrict__ pd_bboxes,
    const int* __restrict__ gt_labels,
    const float* __restrict__ gt_bboxes,
    const float* __restrict__ mask_gt,
    int* fg_inout,      // in: candidate count; out: fg flag (0/1)
    int* assign_inout,  // in: min-m candidate; out: final target gt idx
    float* __restrict__ mval,
    float* __restrict__ pos_align,
    float* __restrict__ pos_ovl) {
    int i = blockIdx.x * blockDim.x + threadIdx.x;
    if (i >= N_TOT) return;
    int b = i / NA, a = i - b * NA;

    int f = fg_inout[i];
    if (f <= 0) {
        fg_inout[i] = 0;
        assign_inout[i] = 0;  // argmax of all-zero column = 0
        mval[i] = 0.f;
        return;
    }

    float ax, ay;
    anchor_xy(a, ax, ay);
    float4 p = ((const float4*)pd_bboxes)[i];

    int m;
    if (f == 1) {
        m = assign_inout[i];
    } else {
        // multi: one_hot(argmax_m overlaps[b,:,a]); ties -> first m
        float best = -1.f;
        int bestm = 0;
        for (int mm = 0; mm < NM; ++mm) {
            float4 gg = ((const float4*)gt_bboxes)[b * NM + mm];
            float dmin = fminf(fminf(ax - gg.x, ay - gg.y),
                               fminf(gg.z - ax, gg.w - ay));
            float ov = 0.f;
            if (dmin > 1e-9f && mask_gt[b * NM + mm] > 0.f)
                ov = ciou_clip(gg.x, gg.y, gg.z, gg.w, p.x, p.y, p.z, p.w);
            if (ov > best) { best = ov; bestm = mm; }
        }
        m = bestm;
    }

    float4 gg = ((const float4*)gt_bboxes)[b * NM + m];
    float dmin = fminf(fminf(ax - gg.x, ay - gg.y), fminf(gg.z - ax, gg.w - ay));
    float mv = 0.f, ovv = 0.f;
    if (dmin > 1e-9f && mask_gt[b * NM + m] > 0.f) {
        ovv = ciou_clip(gg.x, gg.y, gg.z, gg.w, p.x, p.y, p.z, p.w);
        float s = pd_scores[(size_t)i * NC + gt_labels[b * NM + m]];
        float ov2 = ovv * ovv;
        mv = s * ov2 * ov2 * ov2;
    }

    fg_inout[i] = 1;
    assign_inout[i] = m;
    mval[i] = mv;
    // values >= 0 -> int compare == float compare; order-independent.
    atomicMax((int*)&pos_align[b * NM + m], __float_as_int(mv));
    atomicMax((int*)&pos_ovl[b * NM + m], __float_as_int(ovv));
}

// Kernel 3 (fused final + scores): block of 256 anchors. Phase 1 computes
// labels/bboxes/fg/idx + (lbl, norm) into LDS; phase 2 writes the 80-wide
// one-hot scores rows fully coalesced as float4.
__global__ __launch_bounds__(256) void k_fused(
    const int* __restrict__ gt_labels,
    const float* __restrict__ gt_bboxes,
    const int* __restrict__ fgm,
    const int* __restrict__ tgt,
    const float* __restrict__ mval,
    const float* __restrict__ pos_align,
    const float* __restrict__ pos_ovl,
    float* __restrict__ out) {
    __shared__ int   slbl[256];
    __shared__ float snrm[256];
    const int tid = threadIdx.x;
    const int i = blockIdx.x * 256 + tid;

    if (i < N_TOT) {
        int b = i / NA;
        int m = tgt[i];
        int f = fgm[i];
        int lbl = gt_labels[b * NM + m];
        lbl = lbl < 0 ? 0 : lbl;
        float4 box = ((const float4*)gt_bboxes)[b * NM + m];
        float nrm = 0.f;
        if (f) nrm = mval[i] * pos_ovl[b * NM + m] / (pos_align[b * NM + m] + 1e-9f);

        out[i] = (float)lbl;                          // target_labels
        ((float4*)(out + N_TOT))[i] = box;            // target_bboxes
        out[(size_t)85 * N_TOT + i] = f ? 1.f : 0.f;  // fg_mask
        out[(size_t)86 * N_TOT + i] = (float)m;       // target_gt_idx
        slbl[tid] = f ? lbl : -1;
        snrm[tid] = nrm;
    }
    __syncthreads();

    // scores: this block's region = [blockIdx*256*80, +256*80) floats
    float4* out4 = (float4*)(out + (size_t)5 * N_TOT) + (size_t)blockIdx.x * 256 * (NC / 4);
    const int nvec = 256 * (NC / 4);  // 5120 float4
    const int base_anchor = blockIdx.x * 256;
#pragma unroll
    for (int it = 0; it < NC / 4; ++it) {
        int j = it * 256 + tid;
        int il = j / (NC / 4);
        if (base_anchor + il >= N_TOT) break;
        int c0 = (j - il * (NC / 4)) * 4;
        int lbl = slbl[il];
        float4 v = make_float4(0.f, 0.f, 0.f, 0.f);
        if (lbl >= c0 && lbl < c0 + 4) {
            float n = snrm[il];
            if (lbl == c0) v.x = n;
            else if (lbl == c0 + 1) v.y = n;
            else if (lbl == c0 + 2) v.z = n;
            else v.w = n;
        }
        out4[j] = v;
    }
    (void)nvec;
}

extern "C" void kernel_launch(void* const* d_in, const int* in_sizes, int n_in,
                              void* d_out, int out_size, void* d_ws, size_t ws_size,
                              hipStream_t stream) {
    const float* pd_scores = (const float*)d_in[0];
    const float* pd_bboxes = (const float*)d_in[1];
    const int*   gt_labels = (const int*)d_in[3];
    // d_in[2] = anc_points (recomputed in-register), d_in[4] = gt_scores: unused
    const float* gt_bboxes = (const float*)d_in[5];
    const float* mask_gt   = (const float*)d_in[6];
    float* out = (float*)d_out;

    char* ws = (char*)d_ws;
    int*   fg        = (int*)ws;                          // N_TOT i32
    int*   assignm   = (int*)(ws + 4 * (size_t)N_TOT);    // N_TOT i32
    float* mval      = (float*)(ws + 8 * (size_t)N_TOT);  // N_TOT f32
    float* pos_align = (float*)(ws + 12 * (size_t)N_TOT); // BS*NM f32
    float* pos_ovl   = pos_align + BS * NM;               // BS*NM f32

    int nb = (N_TOT + 255) / 256;
    k_init<<<nb, 256, 0, stream>>>(fg, assignm, pos_align);

    k_topk<<<BS * NM, 256, 0, stream>>>(pd_scores, pd_bboxes, gt_labels,
                                        gt_bboxes, mask_gt, fg, assignm);

    k_assign<<<nb, 256, 0, stream>>>(pd_scores, pd_bboxes, gt_labels,
                                     gt_bboxes, mask_gt, fg, assignm, mval,
                                     pos_align, pos_ovl);

    k_fused<<<nb, 256, 0, stream>>>(gt_labels, gt_bboxes, fg, assignm, mval,
                                    pos_align, pos_ovl, out);
}

// Round 5
// 76.751 us; speedup vs baseline: 2.5690x; 1.1196x over previous
//
#include <hip/hip_runtime.h>
#include <math.h>

#define BS 32
#define NM 64
#define NA 8400
#define NC 80
#define TOPKK 13
#define N_TOT (BS * NA)
#define TPL 8  // max candidates per thread: ceil(1840/256)=8 (box<=256px)

// CIoU (box1 = gt, box2 = pred), clipped at 0 — transcribed from the
// reference _ciou with eps=1e-7, then jnp.clip(x, 0).
__device__ __forceinline__ float ciou_clip(float gx1, float gy1, float gx2, float gy2,
                                           float px1, float py1, float px2, float py2) {
    const float eps = 1e-7f;
    float w1 = gx2 - gx1, h1 = gy2 - gy1 + eps;
    float w2 = px2 - px1, h2 = py2 - py1 + eps;
    float iw = fmaxf(fminf(gx2, px2) - fmaxf(gx1, px1), 0.f);
    float ih = fmaxf(fminf(gy2, py2) - fmaxf(gy1, py1), 0.f);
    float inter = iw * ih;
    float uni = w1 * h1 + w2 * h2 - inter + eps;
    float iou = inter / uni;
    float cw = fmaxf(gx2, px2) - fminf(gx1, px1);
    float ch = fmaxf(gy2, py2) - fminf(gy1, py1);
    float c2 = cw * cw + ch * ch + eps;
    float dx = px1 + px2 - gx1 - gx2;
    float dy = py1 + py2 - gy1 - gy2;
    float rho2 = (dx * dx + dy * dy) * 0.25f;
    float dat = atanf(w2 / h2) - atanf(w1 / h1);
    float v = 0.4052847345693511f * dat * dat;  // 4/pi^2
    float al = v / (v - iou + 1.0000001f);      // 1.0 + eps
    return fmaxf(iou - (rho2 / c2 + v * al), 0.f);
}

__device__ __forceinline__ unsigned long long umax64(unsigned long long a,
                                                     unsigned long long b) {
    return a > b ? a : b;
}
__device__ __forceinline__ unsigned long long umin64(unsigned long long a,
                                                     unsigned long long b) {
    return a < b ? a : b;
}

// anchor index -> (ax, ay) exactly: (i+0.5)*stride, bit-identical to reference.
__device__ __forceinline__ void anchor_xy(int a, float& ax, float& ay) {
    int loc, n; float s;
    if (a < 6400)      { loc = a;        n = 80; s = 8.f;  }
    else if (a < 8000) { loc = a - 6400; n = 40; s = 16.f; }
    else               { loc = a - 8000; n = 20; s = 32.f; }
    int row = loc / n, col = loc - row * n;
    ax = ((float)col + 0.5f) * s;
    ay = ((float)row + 0.5f) * s;
}

__global__ __launch_bounds__(256) void k_init(int* __restrict__ fg,
                                              int* __restrict__ assignm,
                                              float* __restrict__ pos) {
    int i = blockIdx.x * blockDim.x + threadIdx.x;
    if (i < N_TOT) {
        fg[i] = 0;
        assignm[i] = 0x7FFFFFFF;
    }
    if (i < 2 * BS * NM) pos[i] = 0.f;
}

// Kernel 1: one 256-thread block per (b, m). Rect-enumerated candidates
// (<=1840, typ ~570), per-lane top-8 in registers (8 = per-lane candidate
// bound, so nothing is ever dropped). Tail = rank-prune, NO shuffle chains:
//   S1: per-wave head-rank via v_readlane loop (register-only). rank>=13
//       => provably excluded. <=13 survivors/wave write heads to LDS.
//   S2: wave 0 ranks the <=52 survivor heads (readlane) -> <=13 global
//       survivors get pool slots.
//   S3: global survivors submit their positive keys to a <=104 LDS pool.
//   S4: pool-rank via broadcast LDS reads; rank<13 <=> true top-13 -> scatter.
//   S5: exact zero-metric filler via 64-lane ballot (nf = 13 - npos).
__global__ __launch_bounds__(256) void k_topk(
    const float* __restrict__ pd_scores,
    const float* __restrict__ pd_bboxes,
    const int* __restrict__ gt_labels,
    const float* __restrict__ gt_bboxes,
    const float* __restrict__ mask_gt,
    int* __restrict__ fg,
    int* __restrict__ assignm) {
    // XCD-aware swizzle (bijective: 2048 % 8 == 0)
    const int bm = ((blockIdx.x & 7) << 8) | (blockIdx.x >> 3);
    if (mask_gt[bm] <= 0.f) return;  // row contributes nothing (count=13@idx0)

    const int tid = threadIdx.x;
    const int lane = tid & 63, wid = tid >> 6;
    const int b = bm / NM;
    const int m = bm - b * NM;
    const float4 g = ((const float4*)gt_bboxes)[bm];
    const int lbl = gt_labels[bm];
    const float4* pb = (const float4*)(pd_bboxes + (size_t)b * NA * 4);
    const float* ps = pd_scores + (size_t)b * NA * NC + lbl;

    __shared__ unsigned long long sheads[4 * TOPKK];  // survivor heads
    __shared__ int sowner[4 * TOPKK];
    __shared__ int ssubmit[256];                      // pool slot or -1
    __shared__ unsigned long long spool[TOPKK * TPL]; // 13 slots x 8 keys
    __shared__ int snpos;

    // LDS init (ordered before survivor writes by B0)
    if (tid < 4 * TOPKK) sheads[tid] = 0ull;
    if (tid < TOPKK * TPL) spool[tid] = 0ull;
    ssubmit[tid] = -1;
    if (tid == 0) snpos = 0;
    __syncthreads();  // B0

    // per-level candidate rects (widened +-1; exact dmin test filters)
    int c0_0, r0_0, w_0, cnt_0, c0_1, r0_1, w_1, cnt_1, c0_2, r0_2, w_2, cnt_2;
    float iw_0, iw_1, iw_2;
    {
#define MKRECT(NN, SS, C0, R0, W, CNT, IW)                                     \
        {                                                                      \
            int c0 = (int)floorf(g.x / SS - 0.5f) - 1; if (c0 < 0) c0 = 0;     \
            int c1 = (int)ceilf (g.z / SS - 0.5f) + 1; if (c1 > NN - 1) c1 = NN - 1; \
            int r0 = (int)floorf(g.y / SS - 0.5f) - 1; if (r0 < 0) r0 = 0;     \
            int r1 = (int)ceilf (g.w / SS - 0.5f) + 1; if (r1 > NN - 1) r1 = NN - 1; \
            int w = c1 - c0 + 1; if (w < 0) w = 0;                             \
            int h = r1 - r0 + 1; if (h < 0) h = 0;                             \
            C0 = c0; R0 = r0; W = w; CNT = w * h; IW = w > 0 ? 1.f / (float)w : 0.f; \
        }
        MKRECT(80, 8.f,  c0_0, r0_0, w_0, cnt_0, iw_0)
        MKRECT(40, 16.f, c0_1, r0_1, w_1, cnt_1, iw_1)
        MKRECT(20, 32.f, c0_2, r0_2, w_2, cnt_2, iw_2)
#undef MKRECT
    }
    const int tot01 = cnt_0 + cnt_1;
    const int total = tot01 + cnt_2;

    unsigned long long t[TPL];
#pragma unroll
    for (int i = 0; i < TPL; ++i) t[i] = 0ull;

#pragma unroll 2
    for (int j = tid; j < total; j += 256) {
        int local, c0, r0, w, base, n; float s, iw;
        if (j < cnt_0)      { local = j;         c0 = c0_0; r0 = r0_0; w = w_0; base = 0;    n = 80; s = 8.f;  iw = iw_0; }
        else if (j < tot01) { local = j - cnt_0; c0 = c0_1; r0 = r0_1; w = w_1; base = 6400; n = 40; s = 16.f; iw = iw_1; }
        else                { local = j - tot01; c0 = c0_2; r0 = r0_2; w = w_2; base = 8000; n = 20; s = 32.f; iw = iw_2; }
        int rr = (int)(((float)local + 0.5f) * iw);  // exact for w<=82
        int cc = local - rr * w;
        int row = r0 + rr, col = c0 + cc;
        float ax = ((float)col + 0.5f) * s;
        float ay = ((float)row + 0.5f) * s;
        float dmin = fminf(fminf(ax - g.x, ay - g.y), fminf(g.z - ax, g.w - ay));
        if (dmin > 1e-9f) {  // exact mask_in_gts (EPS = 1e-9)
            int a = base + row * n + col;
            float4 p = pb[a];
            float ov = ciou_clip(g.x, g.y, g.z, g.w, p.x, p.y, p.z, p.w);
            float sc = ps[(size_t)a * NC];
            float ov2 = ov * ov;
            float metric = sc * ov2 * ov2 * ov2;  // score^1 * overlap^6
            unsigned long long key =
                ((unsigned long long)__float_as_uint(metric) << 32) |
                (unsigned)(NA - 1 - a);
            if (key > t[TPL - 1]) {
#pragma unroll
                for (int i = 0; i < TPL; ++i) {  // static-index sorted insert
                    unsigned long long lo = umin64(t[i], key);
                    t[i] = umax64(t[i], key);
                    key = lo;
                }
            }
        }
    }

    // S1: per-wave head rank (readlane loop — register-only, no LDS pipe)
    {
        unsigned long long h = t[0];
        unsigned hhi = (unsigned)(h >> 32), hlo = (unsigned)h;
        int wrank = 0;
#pragma unroll 8
        for (int l = 0; l < 64; ++l) {
            unsigned ohi = (unsigned)__builtin_amdgcn_readlane((int)hhi, l);
            unsigned olo = (unsigned)__builtin_amdgcn_readlane((int)hlo, l);
            wrank += (ohi > hhi) || (ohi == hhi && olo > hlo);
        }
        if (hhi != 0 && wrank < TOPKK) {  // positive head, wave survivor
            sheads[wid * TOPKK + wrank] = h;
            sowner[wid * TOPKK + wrank] = tid;
        }
    }
    __syncthreads();  // B1

    // S2: wave 0 ranks the <=52 survivor heads
    if (wid == 0) {
        unsigned long long h2 = (lane < 4 * TOPKK) ? sheads[lane] : 0ull;
        unsigned h2hi = (unsigned)(h2 >> 32), h2lo = (unsigned)h2;
        int grank = 0;
#pragma unroll 4
        for (int l = 0; l < 4 * TOPKK; ++l) {
            unsigned ohi = (unsigned)__builtin_amdgcn_readlane((int)h2hi, l);
            unsigned olo = (unsigned)__builtin_amdgcn_readlane((int)h2lo, l);
            grank += (ohi > h2hi) || (ohi == h2hi && olo > h2lo);
        }
        if (lane < 4 * TOPKK && h2hi != 0 && grank < TOPKK)
            ssubmit[sowner[lane]] = grank;
    }
    __syncthreads();  // B2

    // S3: global survivors submit positive keys to pool
    {
        int s = ssubmit[tid];
        if (s >= 0) {
            unsigned long long* dst = &spool[s * TPL];
#pragma unroll
            for (int i = 0; i < TPL; ++i)
                if ((t[i] >> 32) != 0ull) dst[i] = t[i];
        }
    }
    __syncthreads();  // B3

    // S4: pool rank (broadcast LDS reads) -> exact top-13 scatter
    if (tid < TOPKK * TPL) {
        unsigned long long key = spool[tid];
        if ((key >> 32) != 0ull) {
            int rank = 0;
            for (int j = 0; j < TOPKK * TPL; ++j) rank += spool[j] > key;
            if (rank < TOPKK) {
                int a = NA - 1 - (int)(key & 0xFFFFFFFFull);
                atomicAdd(&fg[b * NA + a], 1);
                atomicMin(&assignm[b * NA + a], m);
                atomicAdd(&snpos, 1);
            }
        }
    }
    __syncthreads();  // B4

    // S5: fillers — remaining 13-npos slots = smallest-index zero-metric
    // anchors (provably in indices 0..25 <= 63). In-box fillers scatter.
    if (wid == 0) {
        int nf = TOPKK - snpos;
        if (nf > 0) {
            int f = lane;  // anchor f: level-0 row 0 -> ax=(f+0.5)*8, ay=4
            float ax = ((float)f + 0.5f) * 8.f, ay = 4.0f;
            float dmin = fminf(fminf(ax - g.x, ay - g.y), fminf(g.z - ax, g.w - ay));
            bool inbox = dmin > 1e-9f;
            float metric = 0.f;
            if (inbox) {
                float4 p = pb[f];
                float ov = ciou_clip(g.x, g.y, g.z, g.w, p.x, p.y, p.z, p.w);
                float ov2 = ov * ov;
                metric = ps[(size_t)f * NC] * ov2 * ov2 * ov2;
            }
            bool pos = inbox && (metric > 0.f);
            unsigned long long pmask = __ballot(pos);
            if (inbox && !pos) {
                int rank = __popcll(~pmask & ((1ull << f) - 1ull));
                if (rank < nf) {
                    atomicAdd(&fg[b * NA + f], 1);
                    atomicMin(&assignm[b * NA + f], m);
                }
            }
        }
    }
}

// Kernel 2: one thread per (b, a). Resolve multi-assignment via masked-overlap
// argmax (tie -> lowest m), recompute assigned metric/overlap, reduce
// pos_align/pos_ovl per (b, m).
__global__ __launch_bounds__(256) void k_assign(
    const float* __restrict__ pd_scores,
    const float* __restrict__ pd_bboxes,
    const int* __restrict__ gt_labels,
    const float* __restrict__ gt_bboxes,
    const float* __restrict__ mask_gt,
    int* fg_inout,      // in: candidate count; out: fg flag (0/1)
    int* assign_inout,  // in: min-m candidate; out: final target gt idx
    float* __restrict__ mval,
    float* __restrict__ pos_align,
    float* __restrict__ pos_ovl) {
    int i = blockIdx.x * blockDim.x + threadIdx.x;
    if (i >= N_TOT) return;
    int b = i / NA, a = i - b * NA;

    int f = fg_inout[i];
    if (f <= 0) {
        fg_inout[i] = 0;
        assign_inout[i] = 0;  // argmax of all-zero column = 0
        mval[i] = 0.f;
        return;
    }

    float ax, ay;
    anchor_xy(a, ax, ay);
    float4 p = ((const float4*)pd_bboxes)[i];

    int m;
    if (f == 1) {
        m = assign_inout[i];
    } else {
        // multi: one_hot(argmax_m overlaps[b,:,a]); ties -> first m
        float best = -1.f;
        int bestm = 0;
        for (int mm = 0; mm < NM; ++mm) {
            float4 gg = ((const float4*)gt_bboxes)[b * NM + mm];
            float dmin = fminf(fminf(ax - gg.x, ay - gg.y),
                               fminf(gg.z - ax, gg.w - ay));
            float ov = 0.f;
            if (dmin > 1e-9f && mask_gt[b * NM + mm] > 0.f)
                ov = ciou_clip(gg.x, gg.y, gg.z, gg.w, p.x, p.y, p.z, p.w);
            if (ov > best) { best = ov; bestm = mm; }
        }
        m = bestm;
    }

    float4 gg = ((const float4*)gt_bboxes)[b * NM + m];
    float dmin = fminf(fminf(ax - gg.x, ay - gg.y), fminf(gg.z - ax, gg.w - ay));
    float mv = 0.f, ovv = 0.f;
    if (dmin > 1e-9f && mask_gt[b * NM + m] > 0.f) {
        ovv = ciou_clip(gg.x, gg.y, gg.z, gg.w, p.x, p.y, p.z, p.w);
        float s = pd_scores[(size_t)i * NC + gt_labels[b * NM + m]];
        float ov2 = ovv * ovv;
        mv = s * ov2 * ov2 * ov2;
    }

    fg_inout[i] = 1;
    assign_inout[i] = m;
    mval[i] = mv;
    // values >= 0 -> int compare == float compare; order-independent.
    atomicMax((int*)&pos_align[b * NM + m], __float_as_int(mv));
    atomicMax((int*)&pos_ovl[b * NM + m], __float_as_int(ovv));
}

// Kernel 3 (fused final + scores): block of 256 anchors. Phase 1 computes
// labels/bboxes/fg/idx + (lbl, norm) into LDS; phase 2 writes the 80-wide
// one-hot scores rows fully coalesced as float4.
__global__ __launch_bounds__(256) void k_fused(
    const int* __restrict__ gt_labels,
    const float* __restrict__ gt_bboxes,
    const int* __restrict__ fgm,
    const int* __restrict__ tgt,
    const float* __restrict__ mval,
    const float* __restrict__ pos_align,
    const float* __restrict__ pos_ovl,
    float* __restrict__ out) {
    __shared__ int   slbl[256];
    __shared__ float snrm[256];
    const int tid = threadIdx.x;
    const int i = blockIdx.x * 256 + tid;

    if (i < N_TOT) {
        int b = i / NA;
        int m = tgt[i];
        int f = fgm[i];
        int lbl = gt_labels[b * NM + m];
        lbl = lbl < 0 ? 0 : lbl;
        float4 box = ((const float4*)gt_bboxes)[b * NM + m];
        float nrm = 0.f;
        if (f) nrm = mval[i] * pos_ovl[b * NM + m] / (pos_align[b * NM + m] + 1e-9f);

        out[i] = (float)lbl;                          // target_labels
        ((float4*)(out + N_TOT))[i] = box;            // target_bboxes
        out[(size_t)85 * N_TOT + i] = f ? 1.f : 0.f;  // fg_mask
        out[(size_t)86 * N_TOT + i] = (float)m;       // target_gt_idx
        slbl[tid] = f ? lbl : -1;
        snrm[tid] = nrm;
    }
    __syncthreads();

    // scores: this block's region = [blockIdx*256*80, +256*80) floats
    float4* out4 = (float4*)(out + (size_t)5 * N_TOT) + (size_t)blockIdx.x * 256 * (NC / 4);
    const int base_anchor = blockIdx.x * 256;
#pragma unroll
    for (int it = 0; it < NC / 4; ++it) {
        int j = it * 256 + tid;
        int il = j / (NC / 4);
        if (base_anchor + il >= N_TOT) break;
        int c0 = (j - il * (NC / 4)) * 4;
        int lbl = slbl[il];
        float4 v = make_float4(0.f, 0.f, 0.f, 0.f);
        if (lbl >= c0 && lbl < c0 + 4) {
            float n = snrm[il];
            if (lbl == c0) v.x = n;
            else if (lbl == c0 + 1) v.y = n;
            else if (lbl == c0 + 2) v.z = n;
            else v.w = n;
        }
        out4[j] = v;
    }
}

extern "C" void kernel_launch(void* const* d_in, const int* in_sizes, int n_in,
                              void* d_out, int out_size, void* d_ws, size_t ws_size,
                              hipStream_t stream) {
    const float* pd_scores = (const float*)d_in[0];
    const float* pd_bboxes = (const float*)d_in[1];
    const int*   gt_labels = (const int*)d_in[3];
    // d_in[2] = anc_points (recomputed in-register), d_in[4] = gt_scores: unused
    const float* gt_bboxes = (const float*)d_in[5];
    const float* mask_gt   = (const float*)d_in[6];
    float* out = (float*)d_out;

    char* ws = (char*)d_ws;
    int*   fg        = (int*)ws;                          // N_TOT i32
    int*   assignm   = (int*)(ws + 4 * (size_t)N_TOT);    // N_TOT i32
    float* mval      = (float*)(ws + 8 * (size_t)N_TOT);  // N_TOT f32
    float* pos_align = (float*)(ws + 12 * (size_t)N_TOT); // BS*NM f32
    float* pos_ovl   = pos_align + BS * NM;               // BS*NM f32

    int nb = (N_TOT + 255) / 256;
    k_init<<<nb, 256, 0, stream>>>(fg, assignm, pos_align);

    k_topk<<<BS * NM, 256, 0, stream>>>(pd_scores, pd_bboxes, gt_labels,
                                        gt_bboxes, mask_gt, fg, assignm);

    k_assign<<<nb, 256, 0, stream>>>(pd_scores, pd_bboxes, gt_labels,
                                     gt_bboxes, mask_gt, fg, assignm, mval,
                                     pos_align, pos_ovl);

    k_fused<<<nb, 256, 0, stream>>>(gt_labels, gt_bboxes, fg, assignm, mval,
                                    pos_align, pos_ovl, out);
}

// Round 6
// 75.646 us; speedup vs baseline: 2.6065x; 1.0146x over previous
//
#include <hip/hip_runtime.h>
#include <math.h>

#define BS 32
#define NM 64
#define NA 8400
#define NC 80
#define TOPKK 13
#define N_TOT (BS * NA)
#define TPL 8  // per-lane candidate bound: ceil(1156/256)+ceil(324/256)+1 = 8

// CIoU (box1 = gt, box2 = pred) with gt-side terms hoisted; clipped at 0.
// Bit-identical to the reference _ciou (eps=1e-7) + jnp.clip(x, 0): the
// hoisted values (w1, h1, area1, at1) are computed with identical arithmetic.
__device__ __forceinline__ float ciou_clip_pre(
    float gx1, float gy1, float gx2, float gy2,
    float area1, float at1,
    float px1, float py1, float px2, float py2) {
    const float eps = 1e-7f;
    float w2 = px2 - px1, h2 = py2 - py1 + eps;
    float iw = fmaxf(fminf(gx2, px2) - fmaxf(gx1, px1), 0.f);
    float ih = fmaxf(fminf(gy2, py2) - fmaxf(gy1, py1), 0.f);
    float inter = iw * ih;
    float uni = area1 + w2 * h2 - inter + eps;
    float iou = inter / uni;
    float cw = fmaxf(gx2, px2) - fminf(gx1, px1);
    float ch = fmaxf(gy2, py2) - fminf(gy1, py1);
    float c2 = cw * cw + ch * ch + eps;
    float dx = px1 + px2 - gx1 - gx2;
    float dy = py1 + py2 - gy1 - gy2;
    float rho2 = (dx * dx + dy * dy) * 0.25f;
    float dat = atanf(w2 / h2) - at1;
    float v = 0.4052847345693511f * dat * dat;  // 4/pi^2
    float al = v / (v - iou + 1.0000001f);      // 1.0 + eps
    return fmaxf(iou - (rho2 / c2 + v * al), 0.f);
}

__device__ __forceinline__ unsigned long long umax64(unsigned long long a,
                                                     unsigned long long b) {
    return a > b ? a : b;
}

// anchor index -> (ax, ay) exactly: (i+0.5)*stride, bit-identical to reference.
__device__ __forceinline__ void anchor_xy(int a, float& ax, float& ay) {
    int loc, n; float s;
    if (a < 6400)      { loc = a;        n = 80; s = 8.f;  }
    else if (a < 8000) { loc = a - 6400; n = 40; s = 16.f; }
    else               { loc = a - 8000; n = 20; s = 32.f; }
    int row = loc / n, col = loc - row * n;
    ax = ((float)col + 0.5f) * s;
    ay = ((float)row + 0.5f) * s;
}

__global__ __launch_bounds__(256) void k_init(int* __restrict__ fg,
                                              int* __restrict__ assignm,
                                              float* __restrict__ pos) {
    int i = blockIdx.x * blockDim.x + threadIdx.x;
    if (i < N_TOT) {
        fg[i] = 0;
        assignm[i] = 0x7FFFFFFF;
    }
    if (i < 2 * BS * NM) pos[i] = 0.f;
}

// Kernel 1: one 256-thread block per (b, m). Tight rect candidates (~450),
// three wave-UNIFORM per-level scan loops (no divergent level select), one
// atanf per candidate (gt-side hoisted), shift-register capture (per-lane
// count <= 8 so nothing is dropped), then the R5 rank-prune tail:
//   S1 per-wave head-rank (readlane) -> <=13 survivors/wave
//   S2 wave 0 ranks <=52 heads -> <=13 global survivors w/ pool slots
//   S3 survivors submit positive keys to <=104-entry LDS pool
//   S4 pool-rank; rank<13 <=> exact jax.lax.top_k top-13 -> scatter
//   S5 exact zero-metric filler via 64-lane ballot (nf = 13 - npos)
__global__ __launch_bounds__(256) void k_topk(
    const float* __restrict__ pd_scores,
    const float* __restrict__ pd_bboxes,
    const int* __restrict__ gt_labels,
    const float* __restrict__ gt_bboxes,
    const float* __restrict__ mask_gt,
    int* __restrict__ fg,
    int* __restrict__ assignm) {
    // XCD-aware swizzle (bijective: 2048 % 8 == 0)
    const int bm = ((blockIdx.x & 7) << 8) | (blockIdx.x >> 3);
    if (mask_gt[bm] <= 0.f) return;  // row contributes nothing (count=13@idx0)

    const int tid = threadIdx.x;
    const int lane = tid & 63, wid = tid >> 6;
    const int b = bm / NM;
    const int m = bm - b * NM;
    const float4 g = ((const float4*)gt_bboxes)[bm];
    const int lbl = gt_labels[bm];
    const float4* pb = (const float4*)(pd_bboxes + (size_t)b * NA * 4);
    const float* ps = pd_scores + (size_t)b * NA * NC + lbl;

    // gt-side CIoU invariants (block-uniform)
    const float w1 = g.z - g.x, h1 = g.w - g.y + 1e-7f;
    const float area1 = w1 * h1;
    const float at1 = atanf(w1 / h1);

    __shared__ unsigned long long sheads[4 * TOPKK];
    __shared__ int sowner[4 * TOPKK];
    __shared__ int ssubmit[256];
    __shared__ unsigned long long spool[TOPKK * TPL];
    __shared__ int snpos;

    if (tid < 4 * TOPKK) sheads[tid] = 0ull;
    if (tid < TOPKK * TPL) spool[tid] = 0ull;
    ssubmit[tid] = -1;
    if (tid == 0) snpos = 0;
    __syncthreads();  // B0

    // tight per-level rects (1e-4 margin covers float rounding; the exact
    // dmin test below is the real filter, so rect only needs superset-ness)
    int c0_0, r0_0, w_0, cnt_0, c0_1, r0_1, w_1r, cnt_1, c0_2, r0_2, w_2, cnt_2;
    float iw_0, iw_1, iw_2;
#define MKRECT(NN, INVS, C0, R0, W, CNT, IW)                                   \
    {                                                                          \
        int c0 = (int)floorf(g.x * INVS - 0.5001f); if (c0 < 0) c0 = 0;        \
        int c1 = (int)ceilf (g.z * INVS - 0.4999f); if (c1 > NN - 1) c1 = NN - 1; \
        int r0 = (int)floorf(g.y * INVS - 0.5001f); if (r0 < 0) r0 = 0;        \
        int r1 = (int)ceilf (g.w * INVS - 0.4999f); if (r1 > NN - 1) r1 = NN - 1; \
        int w = c1 - c0 + 1; if (w < 0) w = 0;                                 \
        int h = r1 - r0 + 1; if (h < 0) h = 0;                                 \
        C0 = c0; R0 = r0; W = w; CNT = w * h; IW = w > 0 ? 1.f / (float)w : 0.f; \
    }
    MKRECT(80, 0.125f,   c0_0, r0_0, w_0,  cnt_0, iw_0)
    MKRECT(40, 0.0625f,  c0_1, r0_1, w_1r, cnt_1, iw_1)
    MKRECT(20, 0.03125f, c0_2, r0_2, w_2,  cnt_2, iw_2)
#undef MKRECT

    // shift-register candidate capture (named slots: static indexing only)
    unsigned long long t0 = 0, t1 = 0, t2 = 0, t3 = 0,
                       t4 = 0, t5 = 0, t6 = 0, t7 = 0;

#define PROCESS(AX, AY, A)                                                     \
    {                                                                          \
        float dmin = fminf(fminf((AX) - g.x, (AY) - g.y),                      \
                           fminf(g.z - (AX), g.w - (AY)));                     \
        if (dmin > 1e-9f) { /* exact mask_in_gts (EPS = 1e-9) */               \
            float4 p = pb[A];                                                  \
            float ov = ciou_clip_pre(g.x, g.y, g.z, g.w, area1, at1,           \
                                     p.x, p.y, p.z, p.w);                      \
            float sc = ps[(size_t)(A) * NC];                                   \
            float ov2 = ov * ov;                                               \
            float metric = sc * ov2 * ov2 * ov2; /* score * overlap^6 */       \
            unsigned long long key =                                           \
                ((unsigned long long)__float_as_uint(metric) << 32) |          \
                (unsigned)(NA - 1 - (A));                                      \
            t7 = t6; t6 = t5; t5 = t4; t4 = t3;                                \
            t3 = t2; t2 = t1; t1 = t0; t0 = key;                               \
        }                                                                      \
    }

    for (int j = tid; j < cnt_0; j += 256) {  // level 0: stride 8, n=80
        int rr = (int)(((float)j + 0.5f) * iw_0);
        int cc = j - rr * w_0;
        int row = r0_0 + rr, col = c0_0 + cc;
        float ax = ((float)col + 0.5f) * 8.f;
        float ay = ((float)row + 0.5f) * 8.f;
        PROCESS(ax, ay, row * 80 + col)
    }
    for (int j = tid; j < cnt_1; j += 256) {  // level 1: stride 16, n=40
        int rr = (int)(((float)j + 0.5f) * iw_1);
        int cc = j - rr * w_1r;
        int row = r0_1 + rr, col = c0_1 + cc;
        float ax = ((float)col + 0.5f) * 16.f;
        float ay = ((float)row + 0.5f) * 16.f;
        PROCESS(ax, ay, 6400 + row * 40 + col)
    }
    for (int j = tid; j < cnt_2; j += 256) {  // level 2: stride 32, n=20
        int rr = (int)(((float)j + 0.5f) * iw_2);
        int cc = j - rr * w_2;
        int row = r0_2 + rr, col = c0_2 + cc;
        float ax = ((float)col + 0.5f) * 32.f;
        float ay = ((float)row + 0.5f) * 32.f;
        PROCESS(ax, ay, 8000 + row * 20 + col)
    }
#undef PROCESS

    // S1: per-wave head rank (readlane loop — register-only)
    {
        unsigned long long h =
            umax64(umax64(umax64(t0, t1), umax64(t2, t3)),
                   umax64(umax64(t4, t5), umax64(t6, t7)));
        unsigned hhi = (unsigned)(h >> 32), hlo = (unsigned)h;
        int wrank = 0;
#pragma unroll 8
        for (int l = 0; l < 64; ++l) {
            unsigned ohi = (unsigned)__builtin_amdgcn_readlane((int)hhi, l);
            unsigned olo = (unsigned)__builtin_amdgcn_readlane((int)hlo, l);
            wrank += (ohi > hhi) || (ohi == hhi && olo > hlo);
        }
        if (hhi != 0 && wrank < TOPKK) {
            sheads[wid * TOPKK + wrank] = h;
            sowner[wid * TOPKK + wrank] = tid;
        }
    }
    __syncthreads();  // B1

    // S2: wave 0 ranks the <=52 survivor heads
    if (wid == 0) {
        unsigned long long h2 = (lane < 4 * TOPKK) ? sheads[lane] : 0ull;
        unsigned h2hi = (unsigned)(h2 >> 32), h2lo = (unsigned)h2;
        int grank = 0;
#pragma unroll 4
        for (int l = 0; l < 4 * TOPKK; ++l) {
            unsigned ohi = (unsigned)__builtin_amdgcn_readlane((int)h2hi, l);
            unsigned olo = (unsigned)__builtin_amdgcn_readlane((int)h2lo, l);
            grank += (ohi > h2hi) || (ohi == h2hi && olo > h2lo);
        }
        if (lane < 4 * TOPKK && h2hi != 0 && grank < TOPKK)
            ssubmit[sowner[lane]] = grank;
    }
    __syncthreads();  // B2

    // S3: global survivors submit their positive keys to the pool
    {
        int s = ssubmit[tid];
        if (s >= 0) {
            unsigned long long* dst = &spool[s * TPL];
            if (t0 >> 32) dst[0] = t0;
            if (t1 >> 32) dst[1] = t1;
            if (t2 >> 32) dst[2] = t2;
            if (t3 >> 32) dst[3] = t3;
            if (t4 >> 32) dst[4] = t4;
            if (t5 >> 32) dst[5] = t5;
            if (t6 >> 32) dst[6] = t6;
            if (t7 >> 32) dst[7] = t7;
        }
    }
    __syncthreads();  // B3

    // S4: pool rank (broadcast LDS reads) -> exact top-13 scatter
    if (tid < TOPKK * TPL) {
        unsigned long long key = spool[tid];
        if ((key >> 32) != 0ull) {
            int rank = 0;
            for (int j = 0; j < TOPKK * TPL; ++j) rank += spool[j] > key;
            if (rank < TOPKK) {
                int a = NA - 1 - (int)(key & 0xFFFFFFFFull);
                atomicAdd(&fg[b * NA + a], 1);
                atomicMin(&assignm[b * NA + a], m);
                atomicAdd(&snpos, 1);
            }
        }
    }
    __syncthreads();  // B4

    // S5: fillers — remaining 13-npos slots = smallest-index zero-metric
    // anchors (provably within indices 0..63). In-box fillers scatter.
    if (wid == 0) {
        int nf = TOPKK - snpos;
        if (nf > 0) {
            int f = lane;  // anchor f: level-0 row 0 -> ax=(f+0.5)*8, ay=4
            float ax = ((float)f + 0.5f) * 8.f, ay = 4.0f;
            float dmin = fminf(fminf(ax - g.x, ay - g.y),
                               fminf(g.z - ax, g.w - ay));
            bool inbox = dmin > 1e-9f;
            float metric = 0.f;
            if (inbox) {
                float4 p = pb[f];
                float ov = ciou_clip_pre(g.x, g.y, g.z, g.w, area1, at1,
                                         p.x, p.y, p.z, p.w);
                float ov2 = ov * ov;
                metric = ps[(size_t)f * NC] * ov2 * ov2 * ov2;
            }
            bool pos = inbox && (metric > 0.f);
            unsigned long long pmask = __ballot(pos);
            if (inbox && !pos) {
                int rank = __popcll(~pmask & ((1ull << f) - 1ull));
                if (rank < nf) {
                    atomicAdd(&fg[b * NA + f], 1);
                    atomicMin(&assignm[b * NA + f], m);
                }
            }
        }
    }
}

// Kernel 2: one thread per (b, a). Resolve multi-assignment via masked-overlap
// argmax (tie -> lowest m), recompute assigned metric/overlap, reduce
// pos_align/pos_ovl per (b, m). Pred-side atanf hoisted out of the gt loop.
__global__ __launch_bounds__(256) void k_assign(
    const float* __restrict__ pd_scores,
    const float* __restrict__ pd_bboxes,
    const int* __restrict__ gt_labels,
    const float* __restrict__ gt_bboxes,
    const float* __restrict__ mask_gt,
    int* fg_inout,      // in: candidate count; out: fg flag (0/1)
    int* assign_inout,  // in: min-m candidate; out: final target gt idx
    float* __restrict__ mval,
    float* __restrict__ pos_align,
    float* __restrict__ pos_ovl) {
    int i = blockIdx.x * blockDim.x + threadIdx.x;
    if (i >= N_TOT) return;
    int b = i / NA, a = i - b * NA;

    int f = fg_inout[i];
    if (f <= 0) {
        fg_inout[i] = 0;
        assign_inout[i] = 0;  // argmax of all-zero column = 0
        mval[i] = 0.f;
        return;
    }

    float ax, ay;
    anchor_xy(a, ax, ay);
    float4 p = ((const float4*)pd_bboxes)[i];

    int m;
    if (f == 1) {
        m = assign_inout[i];
    } else {
        // multi: one_hot(argmax_m overlaps[b,:,a]); ties -> first m.
        // NOTE: reference computes _ciou(gt, pred) with box1=gt, so the
        // "w2,h2,atan(w2/h2)" terms are PRED-side -> per-thread uniform here.
        float best = -1.f;
        int bestm = 0;
        for (int mm = 0; mm < NM; ++mm) {
            float4 gg = ((const float4*)gt_bboxes)[b * NM + mm];
            float dmin = fminf(fminf(ax - gg.x, ay - gg.y),
                               fminf(gg.z - ax, gg.w - ay));
            float ov = 0.f;
            if (dmin > 1e-9f && mask_gt[b * NM + mm] > 0.f) {
                float w1 = gg.z - gg.x, h1 = gg.w - gg.y + 1e-7f;
                ov = ciou_clip_pre(gg.x, gg.y, gg.z, gg.w, w1 * h1,
                                   atanf(w1 / h1), p.x, p.y, p.z, p.w);
            }
            if (ov > best) { best = ov; bestm = mm; }
        }
        m = bestm;
    }

    float4 gg = ((const float4*)gt_bboxes)[b * NM + m];
    float dmin = fminf(fminf(ax - gg.x, ay - gg.y), fminf(gg.z - ax, gg.w - ay));
    float mv = 0.f, ovv = 0.f;
    if (dmin > 1e-9f && mask_gt[b * NM + m] > 0.f) {
        float w1 = gg.z - gg.x, h1 = gg.w - gg.y + 1e-7f;
        ovv = ciou_clip_pre(gg.x, gg.y, gg.z, gg.w, w1 * h1, atanf(w1 / h1),
                            p.x, p.y, p.z, p.w);
        float s = pd_scores[(size_t)i * NC + gt_labels[b * NM + m]];
        float ov2 = ovv * ovv;
        mv = s * ov2 * ov2 * ov2;
    }

    fg_inout[i] = 1;
    assign_inout[i] = m;
    mval[i] = mv;
    // values >= 0 -> int compare == float compare; order-independent.
    atomicMax((int*)&pos_align[b * NM + m], __float_as_int(mv));
    atomicMax((int*)&pos_ovl[b * NM + m], __float_as_int(ovv));
}

// Kernel 3 (fused final + scores): block of 256 anchors. Phase 1 computes
// labels/bboxes/fg/idx + (lbl, norm) into LDS; phase 2 writes the 80-wide
// one-hot scores rows fully coalesced as float4.
__global__ __launch_bounds__(256) void k_fused(
    const int* __restrict__ gt_labels,
    const float* __restrict__ gt_bboxes,
    const int* __restrict__ fgm,
    const int* __restrict__ tgt,
    const float* __restrict__ mval,
    const float* __restrict__ pos_align,
    const float* __restrict__ pos_ovl,
    float* __restrict__ out) {
    __shared__ int   slbl[256];
    __shared__ float snrm[256];
    const int tid = threadIdx.x;
    const int i = blockIdx.x * 256 + tid;

    if (i < N_TOT) {
        int b = i / NA;
        int m = tgt[i];
        int f = fgm[i];
        int lbl = gt_labels[b * NM + m];
        lbl = lbl < 0 ? 0 : lbl;
        float4 box = ((const float4*)gt_bboxes)[b * NM + m];
        float nrm = 0.f;
        if (f) nrm = mval[i] * pos_ovl[b * NM + m] / (pos_align[b * NM + m] + 1e-9f);

        out[i] = (float)lbl;                          // target_labels
        ((float4*)(out + N_TOT))[i] = box;            // target_bboxes
        out[(size_t)85 * N_TOT + i] = f ? 1.f : 0.f;  // fg_mask
        out[(size_t)86 * N_TOT + i] = (float)m;       // target_gt_idx
        slbl[tid] = f ? lbl : -1;
        snrm[tid] = nrm;
    }
    __syncthreads();

    float4* out4 = (float4*)(out + (size_t)5 * N_TOT) + (size_t)blockIdx.x * 256 * (NC / 4);
    const int base_anchor = blockIdx.x * 256;
#pragma unroll
    for (int it = 0; it < NC / 4; ++it) {
        int j = it * 256 + tid;
        int il = j / (NC / 4);
        if (base_anchor + il >= N_TOT) break;
        int c0 = (j - il * (NC / 4)) * 4;
        int lbl = slbl[il];
        float4 v = make_float4(0.f, 0.f, 0.f, 0.f);
        if (lbl >= c0 && lbl < c0 + 4) {
            float n = snrm[il];
            if (lbl == c0) v.x = n;
            else if (lbl == c0 + 1) v.y = n;
            else if (lbl == c0 + 2) v.z = n;
            else v.w = n;
        }
        out4[j] = v;
    }
}

extern "C" void kernel_launch(void* const* d_in, const int* in_sizes, int n_in,
                              void* d_out, int out_size, void* d_ws, size_t ws_size,
                              hipStream_t stream) {
    const float* pd_scores = (const float*)d_in[0];
    const float* pd_bboxes = (const float*)d_in[1];
    const int*   gt_labels = (const int*)d_in[3];
    // d_in[2] = anc_points (recomputed in-register), d_in[4] = gt_scores: unused
    const float* gt_bboxes = (const float*)d_in[5];
    const float* mask_gt   = (const float*)d_in[6];
    float* out = (float*)d_out;

    char* ws = (char*)d_ws;
    int*   fg        = (int*)ws;                          // N_TOT i32
    int*   assignm   = (int*)(ws + 4 * (size_t)N_TOT);    // N_TOT i32
    float* mval      = (float*)(ws + 8 * (size_t)N_TOT);  // N_TOT f32
    float* pos_align = (float*)(ws + 12 * (size_t)N_TOT); // BS*NM f32
    float* pos_ovl   = pos_align + BS * NM;               // BS*NM f32

    int nb = (N_TOT + 255) / 256;
    k_init<<<nb, 256, 0, stream>>>(fg, assignm, pos_align);

    k_topk<<<BS * NM, 256, 0, stream>>>(pd_scores, pd_bboxes, gt_labels,
                                        gt_bboxes, mask_gt, fg, assignm);

    k_assign<<<nb, 256, 0, stream>>>(pd_scores, pd_bboxes, gt_labels,
                                     gt_bboxes, mask_gt, fg, assignm, mval,
                                     pos_align, pos_ovl);

    k_fused<<<nb, 256, 0, stream>>>(gt_labels, gt_bboxes, fg, assignm, mval,
                                    pos_align, pos_ovl, out);
}